// Round 6
// baseline (360.969 us; speedup 1.0000x reference)
//
#include <hip/hip_runtime.h>
#include <math.h>

#define D_ 256
#define NS_ 64
#define KNB_ 8
#define SEQ_ 1024
#define B_ 4
#define NEG_ (-10000.0f)
#define BLKNEG_ (-50000.0f)

__device__ __forceinline__ float waveSum(float v) {
#pragma unroll
    for (int off = 32; off; off >>= 1) v += __shfl_xor(v, off, 64);
    return v;
}

__device__ __forceinline__ void waveSum2(float& a, float& b) {
#pragma unroll
    for (int off = 32; off; off >>= 1) {
        a += __shfl_xor(a, off, 64);
        b += __shfl_xor(b, off, 64);
    }
}

// batched block-wide sum of 4 independent values (2 barriers total)
__device__ __forceinline__ void blockSum4(float v[4], float (*scr4)[4]) {
    const int tid = threadIdx.x;
    const int wid = tid >> 6, lane = tid & 63;
#pragma unroll
    for (int off = 32; off; off >>= 1) {
#pragma unroll
        for (int q = 0; q < 4; ++q) v[q] += __shfl_xor(v[q], off, 64);
    }
    __syncthreads();
    if (lane == 0) {
#pragma unroll
        for (int q = 0; q < 4; ++q) scr4[wid][q] = v[q];
    }
    __syncthreads();
#pragma unroll
    for (int q = 0; q < 4; ++q)
        v[q] = scr4[0][q] + scr4[1][q] + scr4[2][q] + scr4[3][q];
}

// exact sparsemax tau via support iteration (monotone, fixpoint = exact tau)
__device__ __forceinline__ float sparsemaxTauWave(const float* zr) {
    float mx = zr[0];
#pragma unroll
    for (int i = 1; i < 16; ++i) mx = fmaxf(mx, zr[i]);
#pragma unroll
    for (int off = 32; off; off >>= 1) mx = fmaxf(mx, __shfl_xor(mx, off, 64));
    float tau = mx - 1.0f;
    for (int it = 0; it < 32; ++it) {
        float ssum = 0.f, cnt = 0.f;
#pragma unroll
        for (int i = 0; i < 16; ++i) {
            if (zr[i] > tau) { ssum += zr[i]; cnt += 1.f; }
        }
        waveSum2(ssum, cnt);
        if (cnt < 0.5f) break;                 // safety
        const float nt = (ssum - 1.0f) / cnt;
        if (nt == tau) break;                  // support stable -> exact
        tau = nt;
    }
    return tau;
}

// 4 transposes + mask-dtype detection in one launch.
__global__ __launch_bounds__(256) void transpose_all(
    const float* __restrict__ messages, const float* __restrict__ scn,
    const float* __restrict__ W_probe, const float* __restrict__ W_vel,
    float* __restrict__ msgT, float* __restrict__ scnT,
    float* __restrict__ WpT, float* __restrict__ WvT,
    const unsigned int* __restrict__ maskW, int* __restrict__ flag)
{
    __shared__ float tile[32][33];
    __shared__ int notI, notF;
    const int bid = blockIdx.x;
    const int tx = threadIdx.x, ty = threadIdx.y;

    if (bid == 1360) {
        const int tid = ty * 32 + tx;
        if (tid == 0) { notI = 0; notF = 0; }
        __syncthreads();
        int ni = 0, nf = 0;
        for (int i = tid; i < 1024; i += 256) {
            const unsigned int w = maskW[i];
            if (w != 0u && w != 1u) ni = 1;
            if (w != 0u && w != 0x3f800000u) nf = 1;
        }
        if (ni) atomicOr(&notI, 1);
        if (nf) atomicOr(&notF, 1);
        __syncthreads();
        if (tid == 0) *flag = (!notI) ? 0 : ((!notF) ? 2 : 1);
        return;
    }

    const float* src; float* dst; int Rr, Cc, bz, cx, cy;
    if (bid < 1024) {
        const int i = bid; bz = i >> 8; const int rem = i & 255;
        cy = rem >> 3; cx = rem & 7;
        src = messages; dst = msgT; Rr = SEQ_; Cc = D_;
    } else if (bid < 1280) {
        const int i = bid - 1024; bz = i >> 6; const int rem = i & 63;
        cy = rem >> 1; cx = rem & 1;
        src = scn; dst = scnT; Rr = SEQ_; Cc = NS_;
    } else if (bid < 1344) {
        const int i = bid - 1280; bz = 0; cy = i >> 3; cx = i & 7;
        src = W_probe; dst = WpT; Rr = D_; Cc = D_;
    } else {
        const int i = bid - 1344; bz = 0; cy = i >> 1; cx = i & 1;
        src = W_vel; dst = WvT; Rr = D_; Cc = NS_;
    }
    const int c0 = cx << 5, r0 = cy << 5;
    const float* s = src + (size_t)bz * Rr * Cc;
    float* d = dst + (size_t)bz * Rr * Cc;
#pragma unroll
    for (int i = 0; i < 32; i += 8)
        tile[ty + i][tx] = s[(size_t)(r0 + ty + i) * Cc + c0 + tx];
    __syncthreads();
#pragma unroll
    for (int i = 0; i < 32; i += 8)
        d[(size_t)(c0 + ty + i) * Rr + r0 + tx] = tile[tx][ty + i];
}

// merged per-row prep, 8 rows per block (512 blocks), A-rows staged in LDS.
__global__ __launch_bounds__(256) void prep8_kernel(
    const float* __restrict__ hidden,
    const float* __restrict__ scn,
    const float* __restrict__ gvel,
    const float* __restrict__ ctx,
    const float* __restrict__ ent,
    const float* __restrict__ WpT,     // [D][D]
    const float* __restrict__ WvT,     // [NS][D]
    const float* __restrict__ W_gate,
    const float* __restrict__ b_gate,
    float* __restrict__ wsEnd,
    float* __restrict__ wsHa,
    float* __restrict__ wsProbe,
    int* __restrict__ wsMode,
    float* __restrict__ wsHn,
    float* __restrict__ wsGw)
{
    __shared__ float scr4[4][4];
    __shared__ float shHd[8 * D_];
    __shared__ float shGv[8 * NS_];
    __shared__ float shSc[8 * NS_];
    const int rowBase = blockIdx.x << 3;
    const int tid = threadIdx.x;
    const int wid = tid >> 6, lane = tid & 63;

    for (int i = tid; i < 8 * D_; i += 256)
        shHd[i] = hidden[(size_t)rowBase * D_ + i];
    for (int i = tid; i < 8 * NS_; i += 256) {
        shGv[i] = gvel[(size_t)rowBase * NS_ + i];
        shSc[i] = scn[(size_t)rowBase * NS_ + i];
    }
    __syncthreads();

    float pr[8] = {};
    for (int e = 0; e < D_; e += 4) {
        const float w0 = WpT[(size_t)(e + 0) * D_ + tid];
        const float w1 = WpT[(size_t)(e + 1) * D_ + tid];
        const float w2 = WpT[(size_t)(e + 2) * D_ + tid];
        const float w3 = WpT[(size_t)(e + 3) * D_ + tid];
#pragma unroll
        for (int r = 0; r < 8; ++r) {
            const float4 h4 = *(const float4*)(shHd + r * D_ + e);
            pr[r] = fmaf(h4.x, w0, fmaf(h4.y, w1, fmaf(h4.z, w2, fmaf(h4.w, w3, pr[r]))));
        }
    }
    float vh[8] = {};
    for (int e = 0; e < NS_; e += 4) {
        const float w0 = WvT[(size_t)(e + 0) * D_ + tid];
        const float w1 = WvT[(size_t)(e + 1) * D_ + tid];
        const float w2 = WvT[(size_t)(e + 2) * D_ + tid];
        const float w3 = WvT[(size_t)(e + 3) * D_ + tid];
#pragma unroll
        for (int r = 0; r < 8; ++r) {
            const float4 g4 = *(const float4*)(shGv + r * NS_ + e);
            vh[r] = fmaf(g4.x, w0, fmaf(g4.y, w1, fmaf(g4.z, w2, fmaf(g4.w, w3, vh[r]))));
        }
    }

    // per-wave: wave w handles rows 2w, 2w+1
#pragma unroll
    for (int rr = 0; rr < 2; ++rr) {
        const int r = (wid << 1) + rr, row = rowBase + r;
        const float sv = shSc[r * NS_ + lane];
        const float gv = shGv[r * NS_ + lane];
        const float e = sv + 0.4f * gv;
        const float ss = waveSum(e * e);
        wsEnd[(size_t)row * NS_ + lane] = e / fmaxf(sqrtf(ss), 1e-12f);
        float v = sv; int idx = lane;
#pragma unroll
        for (int off = 1; off < 64; off <<= 1) {
            const float ov = __shfl_xor(v, off, 64);
            const int   oi = __shfl_xor(idx, off, 64);
            if (ov > v || (ov == v && oi < idx)) { v = ov; idx = oi; }
        }
        float gd = 0.f;
#pragma unroll
        for (int j = 0; j < 4; ++j) {
            const int d = lane + (j << 6);
            gd = fmaf(shHd[r * D_ + d], W_gate[d], gd);
        }
        gd = waveSum(gd);
        if (lane == 0) {
            wsMode[row] = idx;
            const float raw = 1.f / (1.f + expf(-(gd + b_gate[0])));
            wsGw[row] = raw * ctx[row];
            wsHn[row] = ent[row] / 10.373491191781864f;   // log(32000)+1e-8
        }
    }

    // block-wide norms, 4 rows per batched reduction
#pragma unroll
    for (int g = 0; g < 2; ++g) {
        float ha4[4], va[4], vp[4];
#pragma unroll
        for (int q = 0; q < 4; ++q) {
            const int r = (g << 2) + q;
            ha4[q] = shHd[r * D_ + tid] + 0.3f * vh[r];
            va[q] = ha4[q] * ha4[q];
            vp[q] = pr[(g << 2) + q] * pr[(g << 2) + q];
        }
        blockSum4(va, scr4);
        blockSum4(vp, scr4);
#pragma unroll
        for (int q = 0; q < 4; ++q) {
            const int r = (g << 2) + q;
            wsHa[(size_t)(rowBase + r) * D_ + tid] = ha4[q] / fmaxf(sqrtf(va[q]), 1e-12f);
            wsProbe[(size_t)(rowBase + r) * D_ + tid] = pr[r] / fmaxf(sqrtf(vp[q]), 1e-12f);
        }
    }
}

// Kernel A: all-pairs sims -> zg/zl (streaming GEMM, 8 rows/block, A in LDS).
// zl is FINALIZED here (hasNb detection + positional fallback).
__global__ __launch_bounds__(512) void sims_kernel(
    const float* __restrict__ msgT,     // [B][D][S]
    const float* __restrict__ scnT,     // [B][NS][S]
    const float* __restrict__ scn,
    const float* __restrict__ wsHa,
    const float* __restrict__ wsEnd,
    const int* __restrict__ wsMode,
    const float* __restrict__ wsHn,
    const void* __restrict__ maskP,
    const int* __restrict__ maskFlag,
    float* __restrict__ zgO,            // [4096][1024]
    float* __restrict__ zlO)            // [4096][1024]
{
    __shared__ float shH[8 * D_];       // 8 KB
    __shared__ float shE[8 * NS_];      // 2 KB
    __shared__ float shS[8 * NS_];      // 2 KB
    __shared__ int anySh[8];
    const int bid = blockIdx.x;          // 512 blocks
    const int b = bid >> 7;
    const int sBase = (bid & 127) << 3;  // 8 rows
    const int rowBase = (b << 10) + sBase;
    const int tid = threadIdx.x;         // 0..511
    const int lane = tid & 63;
    const int tcol = tid << 1;           // 2 cols

    for (int i = tid; i < 8 * D_; i += 512)
        shH[i] = wsHa[(size_t)rowBase * D_ + i];
    shE[tid] = wsEnd[(size_t)rowBase * NS_ + tid];
    shS[tid] = scn[(size_t)rowBase * NS_ + tid];
    if (tid < 8) anySh[tid] = 0;
    __syncthreads();

    const float* msgTb = msgT + (size_t)b * D_ * SEQ_;
    const float* scnTb = scnT + (size_t)b * NS_ * SEQ_;

    float zh[8][2] = {};
    for (int dc = 0; dc < D_; dc += 4) {
        float2 mv[4];
#pragma unroll
        for (int dj = 0; dj < 4; ++dj)
            mv[dj] = *(const float2*)(msgTb + (size_t)(dc + dj) * SEQ_ + tcol);
#pragma unroll
        for (int r = 0; r < 8; ++r) {
            const float4 h4 = *(const float4*)(shH + r * D_ + dc);
            zh[r][0] = fmaf(h4.x, mv[0].x, fmaf(h4.y, mv[1].x,
                       fmaf(h4.z, mv[2].x, fmaf(h4.w, mv[3].x, zh[r][0]))));
            zh[r][1] = fmaf(h4.x, mv[0].y, fmaf(h4.y, mv[1].y,
                       fmaf(h4.z, mv[2].y, fmaf(h4.w, mv[3].y, zh[r][1]))));
        }
    }
    float ze[8][2] = {}; float zs[8][2] = {};
    for (int dc = 0; dc < NS_; dc += 4) {
        float2 sv[4];
#pragma unroll
        for (int dj = 0; dj < 4; ++dj)
            sv[dj] = *(const float2*)(scnTb + (size_t)(dc + dj) * SEQ_ + tcol);
#pragma unroll
        for (int r = 0; r < 8; ++r) {
            const float4 e4 = *(const float4*)(shE + r * NS_ + dc);
            const float4 s4 = *(const float4*)(shS + r * NS_ + dc);
            ze[r][0] = fmaf(e4.x, sv[0].x, fmaf(e4.y, sv[1].x,
                       fmaf(e4.z, sv[2].x, fmaf(e4.w, sv[3].x, ze[r][0]))));
            ze[r][1] = fmaf(e4.x, sv[0].y, fmaf(e4.y, sv[1].y,
                       fmaf(e4.z, sv[2].y, fmaf(e4.w, sv[3].y, ze[r][1]))));
            zs[r][0] = fmaf(s4.x, sv[0].x, fmaf(s4.y, sv[1].x,
                       fmaf(s4.z, sv[2].x, fmaf(s4.w, sv[3].x, zs[r][0]))));
            zs[r][1] = fmaf(s4.x, sv[0].y, fmaf(s4.y, sv[1].y,
                       fmaf(s4.z, sv[2].y, fmaf(s4.w, sv[3].y, zs[r][1]))));
        }
    }

    const int mf = *maskFlag;
    const int2 md2 = *(const int2*)(wsMode + (b << 10) + tcol);
    float zlc[8][2];
    int any8 = 0;
#pragma unroll
    for (int r = 0; r < 8; ++r) {
        const int s_r = sBase + r;
        const int row = rowBase + r;
        const float Hn = wsHn[row];
        const int mS = wsMode[row];
        int blk0, blk1;
        const size_t mb = (size_t)s_r * SEQ_ + tcol;
        if (mf == 1) {
            const unsigned char* m8 = (const unsigned char*)maskP;
            blk0 = m8[mb] != 0; blk1 = m8[mb + 1] != 0;
        } else if (mf == 2) {
            const float* mfl = (const float*)maskP;
            blk0 = mfl[mb] != 0.f; blk1 = mfl[mb + 1] != 0.f;
        } else {
            const int* m32 = (const int*)maskP;
            blk0 = m32[mb] != 0; blk1 = m32[mb + 1] != 0;
        }
        if (s_r == tcol) blk0 = 1;
        if (s_r == tcol + 1) blk1 = 1;
        const float zg0 = blk0 ? NEG_ : (ze[r][0] * Hn + 0.5f * zh[r][0]) * 5.0f;
        const float zg1 = blk1 ? NEG_ : (ze[r][1] * Hn + 0.5f * zh[r][1]) * 5.0f;
        *(float2*)(zgO + (size_t)row * SEQ_ + tcol) = make_float2(zg0, zg1);
        const int sm0 = (!blk0) && (md2.x == mS);
        const int sm1 = (!blk1) && (md2.y == mS);
        any8 |= (sm0 | sm1) << r;
        zlc[r][0] = sm0 ? zs[r][0] * 5.0f : (blk0 ? BLKNEG_ : 0.0f);
        zlc[r][1] = sm1 ? zs[r][1] * 5.0f : (blk1 ? BLKNEG_ : 0.0f);
    }
#pragma unroll
    for (int r = 0; r < 8; ++r) {
        if (__any((any8 >> r) & 1) && lane == 0) atomicOr(&anySh[r], 1);
    }
    __syncthreads();
#pragma unroll
    for (int r = 0; r < 8; ++r) {
        const int s_r = sBase + r;
        const int row = rowBase + r;
        float zl0 = zlc[r][0], zl1 = zlc[r][1];
        if (!anySh[r]) {
            zl0 = (zl0 == BLKNEG_) ? BLKNEG_ : -0.05f * fabsf((float)(s_r - tcol));
            zl1 = (zl1 == BLKNEG_) ? BLKNEG_ : -0.05f * fabsf((float)(s_r - tcol - 1));
        }
        *(float2*)(zlO + (size_t)row * SEQ_ + tcol) = make_float2(zl0, zl1);
    }
}

// Kernel B: 4 waves per block, wave owns one row (mirror-balanced).
// Combined shfl-free gather list + dense fallback for large sparsemax support.
__global__ __launch_bounds__(256, 4) void route4_kernel(
    const float* __restrict__ messages,
    const float* __restrict__ scn,
    const int* __restrict__ x_ids,
    const int* __restrict__ static_nb,
    const float* __restrict__ W_e1,
    const float* __restrict__ b_e1,
    const float* __restrict__ W_e2,
    const float* __restrict__ b_e2,
    const float* __restrict__ wsProbe,
    const float* __restrict__ wsGw,
    const float* __restrict__ zgA,
    const float* __restrict__ zlA,
    float* __restrict__ out)
{
    __shared__ uint2 lst[4][256];        // combined (t, weight) entries per wave
    __shared__ float wdense[4][1024];    // dense-fallback weights per wave
    __shared__ float ewLds[4][8];
    __shared__ int   mlist[4][64];

    const int jb = blockIdx.x;               // 0..1023
    const int tid = threadIdx.x;
    const int wid = tid >> 6, lane = tid & 63;
    const int base = jb << 1;
    const int row = (wid == 0) ? base
                  : (wid == 1) ? base + 1
                  : (wid == 2) ? 4094 - base
                               : 4095 - base;
    const int b = row >> 10, s_r = row & 1023;
    const float* msgB = messages + (size_t)b * SEQ_ * D_;
    const float* scnB = scn + (size_t)b * SEQ_ * NS_;
    const unsigned long long ltmask = (1ull << lane) - 1ull;
    const int d4 = lane << 2;

    // ----- issue z loads up-front (latency hidden by static branch) -----
    float zrG[16], zrL[16];
    {
        const float4* zgp = (const float4*)(zgA + (size_t)row * SEQ_ + (lane << 4));
        const float4* zlp = (const float4*)(zlA + (size_t)row * SEQ_ + (lane << 4));
#pragma unroll
        for (int q = 0; q < 4; ++q) {
            const float4 g4 = zgp[q];
            zrG[q * 4 + 0] = g4.x; zrG[q * 4 + 1] = g4.y;
            zrG[q * 4 + 2] = g4.z; zrG[q * 4 + 3] = g4.w;
            const float4 l4 = zlp[q];
            zrL[q * 4 + 0] = l4.x; zrL[q * 4 + 1] = l4.y;
            zrL[q * 4 + 2] = l4.z; zrL[q * 4 + 3] = l4.w;
        }
    }

    // ----- static neighbor-vocab branch (independent of z) -----
    const int q = x_ids[row];
    int nb[KNB_];
#pragma unroll
    for (int k = 0; k < KNB_; ++k) nb[k] = static_nb[(size_t)q * KNB_ + k];
    const float ss_l = scnB[(size_t)s_r * NS_ + lane];
    float simk[KNB_] = {};
    int cntk[KNB_] = {};
    int mcW = 0;
    const int* xb = x_ids + (b << 10);
    for (int pb = 0; pb <= s_r; pb += 64) {
        const int p = pb + lane;
        const int id = (p <= s_r) ? xb[p] : -1;
#pragma unroll
        for (int k = 0; k < KNB_; ++k) {
            unsigned long long mbit = __ballot(id == nb[k]);
            if (mbit) {
                cntk[k] += __popcll(mbit);
                while (mbit) {
                    const int src = __ffsll(mbit) - 1;
                    mbit &= mbit - 1;
                    const int pp = pb + src;
                    float pv = scnB[(size_t)pp * NS_ + lane] * ss_l;
                    pv = waveSum(pv);
                    simk[k] += pv;
                    if (mcW < 64) { if (lane == 0) mlist[wid][mcW] = (pp << 3) | k; ++mcW; }
                }
            }
        }
    }
    // edge MLP: lane = k*8 + j computes one gelu term
    const int kk = lane >> 3, jjn = lane & 7;
    float sv = simk[0];
#pragma unroll
    for (int k = 1; k < KNB_; ++k) sv = (kk == k) ? simk[k] : sv;
    const float xx = sv * W_e1[jjn] + b_e1[jjn];
    float eo = 0.5f * xx * (1.f + erff(xx * 0.70710678118654752f)) * W_e2[jjn];
    eo += __shfl_xor(eo, 1, 64); eo += __shfl_xor(eo, 2, 64); eo += __shfl_xor(eo, 4, 64);
    eo += b_e2[0];
    float m2 = eo;
    m2 = fmaxf(m2, __shfl_xor(m2, 8, 64));
    m2 = fmaxf(m2, __shfl_xor(m2, 16, 64));
    m2 = fmaxf(m2, __shfl_xor(m2, 32, 64));
    const float exv = expf(eo - m2);
    float smv = exv;
    smv += __shfl_xor(smv, 8, 64); smv += __shfl_xor(smv, 16, 64); smv += __shfl_xor(smv, 32, 64);
    if ((lane & 7) == 0) ewLds[wid][kk] = exv / smv;

    float cov = 0.f;
#pragma unroll
    for (int k = 0; k < KNB_; ++k) cov += fminf((float)cntk[k], 1.f);
    cov *= 0.125f;

    const float gw = wsGw[row];
    const float coefG = gw;
    const float coefL = (1.f - gw) * (1.f - cov);
    const float coefS = (1.f - gw) * cov;

    int cnt = 0;
    float ox = 0.f, oy = 0.f, oz2 = 0.f, ow = 0.f;

    // ----- geo sparsemax: sparse list or dense fallback -----
    {
        const float tau = sparsemaxTauWave(zrG);
        int sup = 0;
#pragma unroll
        for (int j = 0; j < 16; ++j) sup += __popcll(__ballot(zrG[j] > tau));
        if (sup <= 96) {
#pragma unroll
            for (int j = 0; j < 16; ++j) {
                const float wv = zrG[j] - tau;
                const bool take = wv > 0.f;
                const unsigned long long m = __ballot(take);
                if (take) {
                    const int pos = cnt + __popcll(m & ltmask);
                    lst[wid][pos] = make_uint2((unsigned)((lane << 4) + j),
                                               __float_as_uint(coefG * wv));
                }
                cnt += __popcll(m);
            }
        } else {
#pragma unroll
            for (int qd = 0; qd < 4; ++qd) {
                float4 w4;
                w4.x = coefG * fmaxf(zrG[qd * 4 + 0] - tau, 0.f);
                w4.y = coefG * fmaxf(zrG[qd * 4 + 1] - tau, 0.f);
                w4.z = coefG * fmaxf(zrG[qd * 4 + 2] - tau, 0.f);
                w4.w = coefG * fmaxf(zrG[qd * 4 + 3] - tau, 0.f);
                *(float4*)&wdense[wid][(lane << 4) + qd * 4] = w4;
            }
            for (int t = 0; t < SEQ_; t += 4) {
                const float4 w4 = *(const float4*)&wdense[wid][t];
                if (w4.x > 0.f) { const float4 m4 = *(const float4*)(msgB + (size_t)(t + 0) * D_ + d4);
                    ox = fmaf(w4.x, m4.x, ox); oy = fmaf(w4.x, m4.y, oy); oz2 = fmaf(w4.x, m4.z, oz2); ow = fmaf(w4.x, m4.w, ow); }
                if (w4.y > 0.f) { const float4 m4 = *(const float4*)(msgB + (size_t)(t + 1) * D_ + d4);
                    ox = fmaf(w4.y, m4.x, ox); oy = fmaf(w4.y, m4.y, oy); oz2 = fmaf(w4.y, m4.z, oz2); ow = fmaf(w4.y, m4.w, ow); }
                if (w4.z > 0.f) { const float4 m4 = *(const float4*)(msgB + (size_t)(t + 2) * D_ + d4);
                    ox = fmaf(w4.z, m4.x, ox); oy = fmaf(w4.z, m4.y, oy); oz2 = fmaf(w4.z, m4.z, oz2); ow = fmaf(w4.z, m4.w, ow); }
                if (w4.w > 0.f) { const float4 m4 = *(const float4*)(msgB + (size_t)(t + 3) * D_ + d4);
                    ox = fmaf(w4.w, m4.x, ox); oy = fmaf(w4.w, m4.y, oy); oz2 = fmaf(w4.w, m4.z, oz2); ow = fmaf(w4.w, m4.w, ow); }
            }
        }
    }

    // ----- local sparsemax (hasNb fallback) -----
    {
        int fl = 0;
#pragma unroll
        for (int j = 0; j < 16; ++j) fl |= (zrL[j] != 0.0f && zrL[j] > -40000.f);
        const int hasNb = __any(fl);
        if (!hasNb) {
#pragma unroll
            for (int j = 0; j < 16; ++j) {
                const int t = (lane << 4) + j;
                zrL[j] = (zrL[j] <= -40000.f) ? BLKNEG_ : -0.05f * fabsf((float)(s_r - t));
            }
        }
        const float tau = sparsemaxTauWave(zrL);
        int sup = 0;
#pragma unroll
        for (int j = 0; j < 16; ++j) sup += __popcll(__ballot(zrL[j] > tau));
        if (sup <= 96) {
#pragma unroll
            for (int j = 0; j < 16; ++j) {
                const float wv = zrL[j] - tau;
                const bool take = wv > 0.f;
                const unsigned long long m = __ballot(take);
                if (take) {
                    const int pos = cnt + __popcll(m & ltmask);
                    lst[wid][pos] = make_uint2((unsigned)((lane << 4) + j),
                                               __float_as_uint(coefL * wv));
                }
                cnt += __popcll(m);
            }
        } else {
#pragma unroll
            for (int qd = 0; qd < 4; ++qd) {
                float4 w4;
                w4.x = coefL * fmaxf(zrL[qd * 4 + 0] - tau, 0.f);
                w4.y = coefL * fmaxf(zrL[qd * 4 + 1] - tau, 0.f);
                w4.z = coefL * fmaxf(zrL[qd * 4 + 2] - tau, 0.f);
                w4.w = coefL * fmaxf(zrL[qd * 4 + 3] - tau, 0.f);
                *(float4*)&wdense[wid][(lane << 4) + qd * 4] = w4;
            }
            for (int t = 0; t < SEQ_; t += 4) {
                const float4 w4 = *(const float4*)&wdense[wid][t];
                if (w4.x > 0.f) { const float4 m4 = *(const float4*)(msgB + (size_t)(t + 0) * D_ + d4);
                    ox = fmaf(w4.x, m4.x, ox); oy = fmaf(w4.x, m4.y, oy); oz2 = fmaf(w4.x, m4.z, oz2); ow = fmaf(w4.x, m4.w, ow); }
                if (w4.y > 0.f) { const float4 m4 = *(const float4*)(msgB + (size_t)(t + 1) * D_ + d4);
                    ox = fmaf(w4.y, m4.x, ox); oy = fmaf(w4.y, m4.y, oy); oz2 = fmaf(w4.y, m4.z, oz2); ow = fmaf(w4.y, m4.w, ow); }
                if (w4.z > 0.f) { const float4 m4 = *(const float4*)(msgB + (size_t)(t + 2) * D_ + d4);
                    ox = fmaf(w4.z, m4.x, ox); oy = fmaf(w4.z, m4.y, oy); oz2 = fmaf(w4.z, m4.z, oz2); ow = fmaf(w4.z, m4.w, ow); }
                if (w4.w > 0.f) { const float4 m4 = *(const float4*)(msgB + (size_t)(t + 3) * D_ + d4);
                    ox = fmaf(w4.w, m4.x, ox); oy = fmaf(w4.w, m4.y, oy); oz2 = fmaf(w4.w, m4.z, oz2); ow = fmaf(w4.w, m4.w, ow); }
            }
        }
    }

    // ----- static entries appended (lane-parallel, weight = coefS*ew[k]) -----
    const int nm = (mcW < 64) ? mcW : 64;
    for (int i = lane; i < nm; i += 64) {
        const int ee = mlist[wid][i];
        lst[wid][cnt + i] = make_uint2((unsigned)(ee >> 3),
                                       __float_as_uint(coefS * ewLds[wid][ee & 7]));
    }
    cnt += nm;

    // ----- combined gather, shfl-free, unroll x4 -----
    int i = 0;
    for (; i + 4 <= cnt; i += 4) {
        const uint2 e0 = lst[wid][i + 0];
        const uint2 e1 = lst[wid][i + 1];
        const uint2 e2 = lst[wid][i + 2];
        const uint2 e3 = lst[wid][i + 3];
        const float4 m0 = *(const float4*)(msgB + (size_t)e0.x * D_ + d4);
        const float4 m1 = *(const float4*)(msgB + (size_t)e1.x * D_ + d4);
        const float4 m2b = *(const float4*)(msgB + (size_t)e2.x * D_ + d4);
        const float4 m3 = *(const float4*)(msgB + (size_t)e3.x * D_ + d4);
        const float w0 = __uint_as_float(e0.y), w1 = __uint_as_float(e1.y);
        const float w2 = __uint_as_float(e2.y), w3 = __uint_as_float(e3.y);
        ox = fmaf(w0, m0.x, fmaf(w1, m1.x, fmaf(w2, m2b.x, fmaf(w3, m3.x, ox))));
        oy = fmaf(w0, m0.y, fmaf(w1, m1.y, fmaf(w2, m2b.y, fmaf(w3, m3.y, oy))));
        oz2 = fmaf(w0, m0.z, fmaf(w1, m1.z, fmaf(w2, m2b.z, fmaf(w3, m3.z, oz2))));
        ow = fmaf(w0, m0.w, fmaf(w1, m1.w, fmaf(w2, m2b.w, fmaf(w3, m3.w, ow))));
    }
    for (; i < cnt; ++i) {
        const uint2 e0 = lst[wid][i];
        const float w0 = __uint_as_float(e0.y);
        const float4 m0 = *(const float4*)(msgB + (size_t)e0.x * D_ + d4);
        ox = fmaf(w0, m0.x, ox); oy = fmaf(w0, m0.y, oy);
        oz2 = fmaf(w0, m0.z, oz2); ow = fmaf(w0, m0.w, ow);
    }

    // ----- epilogue: normalize, probe, rel -----
    float ssq = ox * ox + oy * oy + oz2 * oz2 + ow * ow;
    ssq = waveSum(ssq);
    const float nrm = fmaxf(sqrtf(ssq), 1e-12f);
    const float4 pr = *(const float4*)(wsProbe + (size_t)row * D_ + d4);
    float dp = (ox * pr.x + oy * pr.y + oz2 * pr.z + ow * pr.w) / nrm;
    dp = waveSum(dp);
    const float rel = 1.f / (1.f + expf(-dp));
    *(float4*)(out + (size_t)row * D_ + d4) =
        make_float4(ox * rel, oy * rel, oz2 * rel, ow * rel);
}

extern "C" void kernel_launch(void* const* d_in, const int* in_sizes, int n_in,
                              void* d_out, int out_size, void* d_ws, size_t ws_size,
                              hipStream_t stream) {
    const float* messages  = (const float*)d_in[0];
    const float* hidden    = (const float*)d_in[1];
    const int*   x_ids     = (const int*)d_in[2];
    const float* scn       = (const float*)d_in[3];
    const void*  mask      = d_in[4];
    const int*   static_nb = (const int*)d_in[5];
    const float* gvel      = (const float*)d_in[6];
    const float* ctx       = (const float*)d_in[7];
    const float* ent       = (const float*)d_in[8];
    const float* W_vel     = (const float*)d_in[9];
    const float* W_e1      = (const float*)d_in[10];
    const float* b_e1      = (const float*)d_in[11];
    const float* W_e2      = (const float*)d_in[12];
    const float* b_e2      = (const float*)d_in[13];
    const float* W_probe   = (const float*)d_in[14];
    const float* W_gate    = (const float*)d_in[15];
    const float* b_gate    = (const float*)d_in[16];
    float* out = (float*)d_out;
    (void)in_sizes; (void)n_in; (void)out_size; (void)ws_size;

    char* ws = (char*)d_ws;
    size_t o = 0;
    int* flag      = (int*)(ws + o);   o += 256;
    float* wsEnd   = (float*)(ws + o); o += (size_t)B_ * SEQ_ * NS_ * 4;
    float* wsHa    = (float*)(ws + o); o += (size_t)B_ * SEQ_ * D_ * 4;
    float* wsProbe = (float*)(ws + o); o += (size_t)B_ * SEQ_ * D_ * 4;
    int* wsMode    = (int*)(ws + o);   o += (size_t)B_ * SEQ_ * 4;
    float* wsHn    = (float*)(ws + o); o += (size_t)B_ * SEQ_ * 4;
    float* wsGw    = (float*)(ws + o); o += (size_t)B_ * SEQ_ * 4;
    float* msgT    = (float*)(ws + o); o += (size_t)B_ * D_ * SEQ_ * 4;
    float* scnT    = (float*)(ws + o); o += (size_t)B_ * NS_ * SEQ_ * 4;
    float* WpT     = (float*)(ws + o); o += (size_t)D_ * D_ * 4;
    float* WvT     = (float*)(ws + o); o += (size_t)D_ * NS_ * 4;
    float* zgW     = (float*)(ws + o); o += (size_t)B_ * SEQ_ * SEQ_ * 4;
    float* zlW     = (float*)(ws + o); o += (size_t)B_ * SEQ_ * SEQ_ * 4;

    transpose_all<<<dim3(1361), dim3(32, 8), 0, stream>>>(
        messages, scn, W_probe, W_vel, msgT, scnT, WpT, WvT,
        (const unsigned int*)mask, flag);
    prep8_kernel<<<dim3(B_ * SEQ_ / 8), dim3(256), 0, stream>>>(
        hidden, scn, gvel, ctx, ent, WpT, WvT, W_gate, b_gate,
        wsEnd, wsHa, wsProbe, wsMode, wsHn, wsGw);
    sims_kernel<<<dim3(512), dim3(512), 0, stream>>>(
        msgT, scnT, scn, wsHa, wsEnd, wsMode, wsHn, mask, flag, zgW, zlW);
    route4_kernel<<<dim3(B_ * SEQ_ / 4), dim3(256), 0, stream>>>(
        messages, scn, x_ids, static_nb, W_e1, b_e1, W_e2, b_e2,
        wsProbe, wsGw, zgW, zlW, out);
}

// Round 7
// 175.237 us; speedup vs baseline: 2.0599x; 2.0599x over previous
//
#include <hip/hip_runtime.h>
#include <math.h>

#define D_ 256
#define NS_ 64
#define KNB_ 8
#define SEQ_ 1024
#define B_ 4
#define MAXQ_ 1024
#define NEG_ (-10000.0f)
#define BLKNEG_ (-50000.0f)

__device__ __forceinline__ float waveSum(float v) {
#pragma unroll
    for (int off = 32; off; off >>= 1) v += __shfl_xor(v, off, 64);
    return v;
}

__device__ __forceinline__ void waveSum2(float& a, float& b) {
#pragma unroll
    for (int off = 32; off; off >>= 1) {
        a += __shfl_xor(a, off, 64);
        b += __shfl_xor(b, off, 64);
    }
}

__device__ __forceinline__ float blockSum(float v, float* scr) {
    const int tid = threadIdx.x;
    const int wid = tid >> 6, lane = tid & 63;
    v = waveSum(v);
    __syncthreads();
    if (lane == 0) scr[wid] = v;
    __syncthreads();
    return scr[0] + scr[1] + scr[2] + scr[3];
}

// batched block-wide sum of 4 independent values (2 barriers total)
__device__ __forceinline__ void blockSum4(float v[4], float (*scr4)[4]) {
    const int tid = threadIdx.x;
    const int wid = tid >> 6, lane = tid & 63;
#pragma unroll
    for (int off = 32; off; off >>= 1) {
#pragma unroll
        for (int q = 0; q < 4; ++q) v[q] += __shfl_xor(v[q], off, 64);
    }
    __syncthreads();
    if (lane == 0) {
#pragma unroll
        for (int q = 0; q < 4; ++q) scr4[wid][q] = v[q];
    }
    __syncthreads();
#pragma unroll
    for (int q = 0; q < 4; ++q)
        v[q] = scr4[0][q] + scr4[1][q] + scr4[2][q] + scr4[3][q];
}

// exact sparsemax tau via support iteration (monotone, fixpoint = exact tau)
__device__ __forceinline__ float sparsemaxTauWave(const float* zr) {
    float mx = zr[0];
#pragma unroll
    for (int i = 1; i < 16; ++i) mx = fmaxf(mx, zr[i]);
#pragma unroll
    for (int off = 32; off; off >>= 1) mx = fmaxf(mx, __shfl_xor(mx, off, 64));
    float tau = mx - 1.0f;
    for (int it = 0; it < 32; ++it) {
        float ssum = 0.f, cnt = 0.f;
#pragma unroll
        for (int i = 0; i < 16; ++i) {
            if (zr[i] > tau) { ssum += zr[i]; cnt += 1.f; }
        }
        waveSum2(ssum, cnt);
        if (cnt < 0.5f) break;                 // safety
        const float nt = (ssum - 1.0f) / cnt;
        if (nt == tau) break;                  // support stable -> exact
        tau = nt;
    }
    return tau;
}

// 4 transposes + mask-dtype detection + queue-counter zeroing in one launch.
__global__ __launch_bounds__(256) void transpose_all(
    const float* __restrict__ messages, const float* __restrict__ scn,
    const float* __restrict__ W_probe, const float* __restrict__ W_vel,
    float* __restrict__ msgT, float* __restrict__ scnT,
    float* __restrict__ WpT, float* __restrict__ WvT,
    const unsigned int* __restrict__ maskW, int* __restrict__ flag,
    int* __restrict__ qMeta)
{
    __shared__ float tile[32][33];
    __shared__ int notI, notF;
    const int bid = blockIdx.x;
    const int tx = threadIdx.x, ty = threadIdx.y;

    if (bid == 1360) {
        const int tid = ty * 32 + tx;
        if (tid == 0) { notI = 0; notF = 0; qMeta[0] = 0; qMeta[1] = 0; }
        __syncthreads();
        int ni = 0, nf = 0;
        for (int i = tid; i < 1024; i += 256) {
            const unsigned int w = maskW[i];
            if (w != 0u && w != 1u) ni = 1;
            if (w != 0u && w != 0x3f800000u) nf = 1;
        }
        if (ni) atomicOr(&notI, 1);
        if (nf) atomicOr(&notF, 1);
        __syncthreads();
        if (tid == 0) *flag = (!notI) ? 0 : ((!notF) ? 2 : 1);
        return;
    }

    const float* src; float* dst; int Rr, Cc, bz, cx, cy;
    if (bid < 1024) {
        const int i = bid; bz = i >> 8; const int rem = i & 255;
        cy = rem >> 3; cx = rem & 7;
        src = messages; dst = msgT; Rr = SEQ_; Cc = D_;
    } else if (bid < 1280) {
        const int i = bid - 1024; bz = i >> 6; const int rem = i & 63;
        cy = rem >> 1; cx = rem & 1;
        src = scn; dst = scnT; Rr = SEQ_; Cc = NS_;
    } else if (bid < 1344) {
        const int i = bid - 1280; bz = 0; cy = i >> 3; cx = i & 7;
        src = W_probe; dst = WpT; Rr = D_; Cc = D_;
    } else {
        const int i = bid - 1344; bz = 0; cy = i >> 1; cx = i & 1;
        src = W_vel; dst = WvT; Rr = D_; Cc = NS_;
    }
    const int c0 = cx << 5, r0 = cy << 5;
    const float* s = src + (size_t)bz * Rr * Cc;
    float* d = dst + (size_t)bz * Rr * Cc;
#pragma unroll
    for (int i = 0; i < 32; i += 8)
        tile[ty + i][tx] = s[(size_t)(r0 + ty + i) * Cc + c0 + tx];
    __syncthreads();
#pragma unroll
    for (int i = 0; i < 32; i += 8)
        d[(size_t)(c0 + ty + i) * Rr + r0 + tx] = tile[tx][ty + i];
}

// merged per-row prep, 8 rows per block (512 blocks) — round-5 form (no LDS staging).
__global__ __launch_bounds__(256) void prep8_kernel(
    const float* __restrict__ hidden,
    const float* __restrict__ scn,
    const float* __restrict__ gvel,
    const float* __restrict__ ctx,
    const float* __restrict__ ent,
    const float* __restrict__ WpT,     // [D][D]
    const float* __restrict__ WvT,     // [NS][D]
    const float* __restrict__ W_gate,
    const float* __restrict__ b_gate,
    float* __restrict__ wsEnd,
    float* __restrict__ wsHa,
    float* __restrict__ wsProbe,
    int* __restrict__ wsMode,
    float* __restrict__ wsHn,
    float* __restrict__ wsGw)
{
    __shared__ float scr4[4][4];
    const int rowBase = blockIdx.x << 3;
    const int tid = threadIdx.x;
    const int wid = tid >> 6, lane = tid & 63;
    const float* h0 = hidden + (size_t)rowBase * D_;

    float pr[8] = {};
    for (int e = 0; e < D_; e += 4) {
        const float w0 = WpT[(size_t)(e + 0) * D_ + tid];
        const float w1 = WpT[(size_t)(e + 1) * D_ + tid];
        const float w2 = WpT[(size_t)(e + 2) * D_ + tid];
        const float w3 = WpT[(size_t)(e + 3) * D_ + tid];
#pragma unroll
        for (int r = 0; r < 8; ++r) {
            const float4 h4 = *(const float4*)(h0 + (size_t)r * D_ + e);  // uniform
            pr[r] = fmaf(h4.x, w0, fmaf(h4.y, w1, fmaf(h4.z, w2, fmaf(h4.w, w3, pr[r]))));
        }
    }
    float vh[8] = {};
    for (int e = 0; e < NS_; e += 4) {
        const float w0 = WvT[(size_t)(e + 0) * D_ + tid];
        const float w1 = WvT[(size_t)(e + 1) * D_ + tid];
        const float w2 = WvT[(size_t)(e + 2) * D_ + tid];
        const float w3 = WvT[(size_t)(e + 3) * D_ + tid];
#pragma unroll
        for (int r = 0; r < 8; ++r) {
            const float4 g4 = *(const float4*)(gvel + (size_t)(rowBase + r) * NS_ + e);
            vh[r] = fmaf(g4.x, w0, fmaf(g4.y, w1, fmaf(g4.z, w2, fmaf(g4.w, w3, vh[r]))));
        }
    }

    // per-wave: wave w handles rows 2w, 2w+1
#pragma unroll
    for (int rr = 0; rr < 2; ++rr) {
        const int r = (wid << 1) + rr, row = rowBase + r;
        const float sv = scn[(size_t)row * NS_ + lane];
        const float gv = gvel[(size_t)row * NS_ + lane];
        const float e = sv + 0.4f * gv;
        const float ss = waveSum(e * e);
        wsEnd[(size_t)row * NS_ + lane] = e / fmaxf(sqrtf(ss), 1e-12f);
        float v = sv; int idx = lane;
#pragma unroll
        for (int off = 1; off < 64; off <<= 1) {
            const float ov = __shfl_xor(v, off, 64);
            const int   oi = __shfl_xor(idx, off, 64);
            if (ov > v || (ov == v && oi < idx)) { v = ov; idx = oi; }
        }
        float gd = 0.f;
#pragma unroll
        for (int j = 0; j < 4; ++j) {
            const int d = lane + (j << 6);
            gd = fmaf(h0[(size_t)r * D_ + d], W_gate[d], gd);
        }
        gd = waveSum(gd);
        if (lane == 0) {
            wsMode[row] = idx;
            const float raw = 1.f / (1.f + expf(-(gd + b_gate[0])));
            wsGw[row] = raw * ctx[row];
            wsHn[row] = ent[row] / 10.373491191781864f;   // log(32000)+1e-8
        }
    }

    // block-wide norms, 4 rows per batched reduction
#pragma unroll
    for (int g = 0; g < 2; ++g) {
        float ha4[4], va[4], vp[4];
#pragma unroll
        for (int q = 0; q < 4; ++q) {
            const int r = (g << 2) + q;
            ha4[q] = h0[(size_t)r * D_ + tid] + 0.3f * vh[r];
            va[q] = ha4[q] * ha4[q];
            vp[q] = pr[(g << 2) + q] * pr[(g << 2) + q];
        }
        blockSum4(va, scr4);
        blockSum4(vp, scr4);
#pragma unroll
        for (int q = 0; q < 4; ++q) {
            const int r = (g << 2) + q;
            wsHa[(size_t)(rowBase + r) * D_ + tid] = ha4[q] / fmaxf(sqrtf(va[q]), 1e-12f);
            wsProbe[(size_t)(rowBase + r) * D_ + tid] = pr[r] / fmaxf(sqrtf(vp[q]), 1e-12f);
        }
    }
}

// Kernel A: all-pairs sims -> zg/zl (streaming GEMM, 8 rows/block, A in LDS).
// zl is FINALIZED here (hasNb detection + positional fallback).
__global__ __launch_bounds__(512) void sims_kernel(
    const float* __restrict__ msgT,     // [B][D][S]
    const float* __restrict__ scnT,     // [B][NS][S]
    const float* __restrict__ scn,
    const float* __restrict__ wsHa,
    const float* __restrict__ wsEnd,
    const int* __restrict__ wsMode,
    const float* __restrict__ wsHn,
    const void* __restrict__ maskP,
    const int* __restrict__ maskFlag,
    float* __restrict__ zgO,            // [4096][1024]
    float* __restrict__ zlO)            // [4096][1024]
{
    __shared__ float shH[8 * D_];       // 8 KB
    __shared__ float shE[8 * NS_];      // 2 KB
    __shared__ float shS[8 * NS_];      // 2 KB
    __shared__ int anySh[8];
    const int bid = blockIdx.x;          // 512 blocks
    const int b = bid >> 7;
    const int sBase = (bid & 127) << 3;  // 8 rows
    const int rowBase = (b << 10) + sBase;
    const int tid = threadIdx.x;         // 0..511
    const int lane = tid & 63;
    const int tcol = tid << 1;           // 2 cols

    for (int i = tid; i < 8 * D_; i += 512)
        shH[i] = wsHa[(size_t)rowBase * D_ + i];
    shE[tid] = wsEnd[(size_t)rowBase * NS_ + tid];
    shS[tid] = scn[(size_t)rowBase * NS_ + tid];
    if (tid < 8) anySh[tid] = 0;
    __syncthreads();

    const float* msgTb = msgT + (size_t)b * D_ * SEQ_;
    const float* scnTb = scnT + (size_t)b * NS_ * SEQ_;

    float zh[8][2] = {};
    for (int dc = 0; dc < D_; dc += 4) {
        float2 mv[4];
#pragma unroll
        for (int dj = 0; dj < 4; ++dj)
            mv[dj] = *(const float2*)(msgTb + (size_t)(dc + dj) * SEQ_ + tcol);
#pragma unroll
        for (int r = 0; r < 8; ++r) {
            const float4 h4 = *(const float4*)(shH + r * D_ + dc);
            zh[r][0] = fmaf(h4.x, mv[0].x, fmaf(h4.y, mv[1].x,
                       fmaf(h4.z, mv[2].x, fmaf(h4.w, mv[3].x, zh[r][0]))));
            zh[r][1] = fmaf(h4.x, mv[0].y, fmaf(h4.y, mv[1].y,
                       fmaf(h4.z, mv[2].y, fmaf(h4.w, mv[3].y, zh[r][1]))));
        }
    }
    float ze[8][2] = {}; float zs[8][2] = {};
    for (int dc = 0; dc < NS_; dc += 4) {
        float2 sv[4];
#pragma unroll
        for (int dj = 0; dj < 4; ++dj)
            sv[dj] = *(const float2*)(scnTb + (size_t)(dc + dj) * SEQ_ + tcol);
#pragma unroll
        for (int r = 0; r < 8; ++r) {
            const float4 e4 = *(const float4*)(shE + r * NS_ + dc);
            const float4 s4 = *(const float4*)(shS + r * NS_ + dc);
            ze[r][0] = fmaf(e4.x, sv[0].x, fmaf(e4.y, sv[1].x,
                       fmaf(e4.z, sv[2].x, fmaf(e4.w, sv[3].x, ze[r][0]))));
            ze[r][1] = fmaf(e4.x, sv[0].y, fmaf(e4.y, sv[1].y,
                       fmaf(e4.z, sv[2].y, fmaf(e4.w, sv[3].y, ze[r][1]))));
            zs[r][0] = fmaf(s4.x, sv[0].x, fmaf(s4.y, sv[1].x,
                       fmaf(s4.z, sv[2].x, fmaf(s4.w, sv[3].x, zs[r][0]))));
            zs[r][1] = fmaf(s4.x, sv[0].y, fmaf(s4.y, sv[1].y,
                       fmaf(s4.z, sv[2].y, fmaf(s4.w, sv[3].y, zs[r][1]))));
        }
    }

    const int mf = *maskFlag;
    const int2 md2 = *(const int2*)(wsMode + (b << 10) + tcol);
    float zlc[8][2];
    int any8 = 0;
#pragma unroll
    for (int r = 0; r < 8; ++r) {
        const int s_r = sBase + r;
        const int row = rowBase + r;
        const float Hn = wsHn[row];
        const int mS = wsMode[row];
        int blk0, blk1;
        const size_t mb = (size_t)s_r * SEQ_ + tcol;
        if (mf == 1) {
            const unsigned char* m8 = (const unsigned char*)maskP;
            blk0 = m8[mb] != 0; blk1 = m8[mb + 1] != 0;
        } else if (mf == 2) {
            const float* mfl = (const float*)maskP;
            blk0 = mfl[mb] != 0.f; blk1 = mfl[mb + 1] != 0.f;
        } else {
            const int* m32 = (const int*)maskP;
            blk0 = m32[mb] != 0; blk1 = m32[mb + 1] != 0;
        }
        if (s_r == tcol) blk0 = 1;
        if (s_r == tcol + 1) blk1 = 1;
        const float zg0 = blk0 ? NEG_ : (ze[r][0] * Hn + 0.5f * zh[r][0]) * 5.0f;
        const float zg1 = blk1 ? NEG_ : (ze[r][1] * Hn + 0.5f * zh[r][1]) * 5.0f;
        *(float2*)(zgO + (size_t)row * SEQ_ + tcol) = make_float2(zg0, zg1);
        const int sm0 = (!blk0) && (md2.x == mS);
        const int sm1 = (!blk1) && (md2.y == mS);
        any8 |= (sm0 | sm1) << r;
        zlc[r][0] = sm0 ? zs[r][0] * 5.0f : (blk0 ? BLKNEG_ : 0.0f);
        zlc[r][1] = sm1 ? zs[r][1] * 5.0f : (blk1 ? BLKNEG_ : 0.0f);
    }
#pragma unroll
    for (int r = 0; r < 8; ++r) {
        if (__any((any8 >> r) & 1) && lane == 0) atomicOr(&anySh[r], 1);
    }
    __syncthreads();
#pragma unroll
    for (int r = 0; r < 8; ++r) {
        const int s_r = sBase + r;
        const int row = rowBase + r;
        float zl0 = zlc[r][0], zl1 = zlc[r][1];
        if (!anySh[r]) {
            zl0 = (zl0 == BLKNEG_) ? BLKNEG_ : -0.05f * fabsf((float)(s_r - tcol));
            zl1 = (zl1 == BLKNEG_) ? BLKNEG_ : -0.05f * fabsf((float)(s_r - tcol - 1));
        }
        *(float2*)(zlO + (size_t)row * SEQ_ + tcol) = make_float2(zl0, zl1);
    }
}

// Kernel B: 4 waves per block, wave owns one row (mirror-balanced).
// Sparse combined gather; dense-support rows deferred to cleanup via queue.
__global__ __launch_bounds__(256) void route4_kernel(
    const float* __restrict__ messages,
    const float* __restrict__ scn,
    const int* __restrict__ x_ids,
    const int* __restrict__ static_nb,
    const float* __restrict__ W_e1,
    const float* __restrict__ b_e1,
    const float* __restrict__ W_e2,
    const float* __restrict__ b_e2,
    const float* __restrict__ wsProbe,
    const float* __restrict__ wsGw,
    const float* __restrict__ zgA,
    const float* __restrict__ zlA,
    float* __restrict__ wq,          // [MAXQ][1024] dense weights
    int* __restrict__ qRows,
    int* __restrict__ qMeta,         // [0]=tail, [1]=consume
    float* __restrict__ out)
{
    __shared__ uint2 lst[4][256];        // combined (t, weight) entries per wave
    __shared__ float ewLds[4][8];
    __shared__ int   mlist[4][64];

    const int jb = blockIdx.x;               // 0..1023
    const int tid = threadIdx.x;
    const int wid = tid >> 6, lane = tid & 63;
    const int base = jb << 1;
    const int row = (wid == 0) ? base
                  : (wid == 1) ? base + 1
                  : (wid == 2) ? 4094 - base
                               : 4095 - base;
    const int b = row >> 10, s_r = row & 1023;
    const float* msgB = messages + (size_t)b * SEQ_ * D_;
    const float* scnB = scn + (size_t)b * SEQ_ * NS_;
    const unsigned long long ltmask = (1ull << lane) - 1ull;
    const int d4 = lane << 2;

    // ----- issue z loads up-front (latency hidden by static branch) -----
    float zrG[16], zrL[16];
    {
        const float4* zgp = (const float4*)(zgA + (size_t)row * SEQ_ + (lane << 4));
        const float4* zlp = (const float4*)(zlA + (size_t)row * SEQ_ + (lane << 4));
#pragma unroll
        for (int q = 0; q < 4; ++q) {
            const float4 g4 = zgp[q];
            zrG[q * 4 + 0] = g4.x; zrG[q * 4 + 1] = g4.y;
            zrG[q * 4 + 2] = g4.z; zrG[q * 4 + 3] = g4.w;
            const float4 l4 = zlp[q];
            zrL[q * 4 + 0] = l4.x; zrL[q * 4 + 1] = l4.y;
            zrL[q * 4 + 2] = l4.z; zrL[q * 4 + 3] = l4.w;
        }
    }

    // ----- static neighbor-vocab scan: ONE ballot per 64-block (kmask) -----
    const int q = x_ids[row];
    int nb[KNB_];
#pragma unroll
    for (int k = 0; k < KNB_; ++k) nb[k] = static_nb[(size_t)q * KNB_ + k];
    const float ss_l = scnB[(size_t)s_r * NS_ + lane];
    float simk[KNB_] = {};
    unsigned matchedMask = 0;
    int mcW = 0;
    const int* xb = x_ids + (b << 10);
    for (int pb = 0; pb <= s_r; pb += 64) {
        const int p = pb + lane;
        const int id = (p <= s_r) ? xb[p] : -2147483647;
        unsigned kmask = 0;
#pragma unroll
        for (int k = 0; k < KNB_; ++k) kmask |= (id == nb[k]) ? (1u << k) : 0u;
        unsigned long long mb = __ballot(kmask != 0u);
        while (mb) {
            const int src = __ffsll(mb) - 1; mb &= mb - 1;
            const unsigned kms = (unsigned)__shfl((int)kmask, src, 64);
            const int pp = pb + src;
            float pv = scnB[(size_t)pp * NS_ + lane] * ss_l;
            pv = waveSum(pv);
            matchedMask |= kms;
#pragma unroll
            for (int k = 0; k < KNB_; ++k) {
                if ((kms >> k) & 1u) {
                    simk[k] += pv;
                    if (mcW < 64) { if (lane == 0) mlist[wid][mcW] = (pp << 3) | k; ++mcW; }
                }
            }
        }
    }
    // edge MLP: lane = k*8 + j computes one gelu term
    const int kk = lane >> 3, jjn = lane & 7;
    float sv = simk[0];
#pragma unroll
    for (int k = 1; k < KNB_; ++k) sv = (kk == k) ? simk[k] : sv;
    const float xx = sv * W_e1[jjn] + b_e1[jjn];
    float eo = 0.5f * xx * (1.f + erff(xx * 0.70710678118654752f)) * W_e2[jjn];
    eo += __shfl_xor(eo, 1, 64); eo += __shfl_xor(eo, 2, 64); eo += __shfl_xor(eo, 4, 64);
    eo += b_e2[0];
    float m2 = eo;
    m2 = fmaxf(m2, __shfl_xor(m2, 8, 64));
    m2 = fmaxf(m2, __shfl_xor(m2, 16, 64));
    m2 = fmaxf(m2, __shfl_xor(m2, 32, 64));
    const float exv = expf(eo - m2);
    float smv = exv;
    smv += __shfl_xor(smv, 8, 64); smv += __shfl_xor(smv, 16, 64); smv += __shfl_xor(smv, 32, 64);
    if ((lane & 7) == 0) ewLds[wid][kk] = exv / smv;

    const float cov = (float)__popc(matchedMask) * 0.125f;
    const float gw = wsGw[row];
    const float coefG = gw;
    const float coefL = (1.f - gw) * (1.f - cov);
    const float coefS = (1.f - gw) * cov;

    // ----- sparsemax taus + support sizes -----
    const float tauG = sparsemaxTauWave(zrG);
    int supG = 0;
#pragma unroll
    for (int j = 0; j < 16; ++j) supG += __popcll(__ballot(zrG[j] > tauG));
    const float tauL = sparsemaxTauWave(zrL);
    int supL = 0;
#pragma unroll
    for (int j = 0; j < 16; ++j) supL += __popcll(__ballot(zrL[j] > tauL));
    const bool gDense = supG > 96;
    const bool lDense = supL > 96;

    // ----- sparse list build (only for non-dense branches) -----
    int cnt = 0;
    if (!gDense) {
#pragma unroll
        for (int j = 0; j < 16; ++j) {
            const float wv = zrG[j] - tauG;
            const bool take = wv > 0.f;
            const unsigned long long m = __ballot(take);
            if (take) {
                const int pos = cnt + __popcll(m & ltmask);
                lst[wid][pos] = make_uint2((unsigned)((lane << 4) + j),
                                           __float_as_uint(coefG * wv));
            }
            cnt += __popcll(m);
        }
    }
    if (!lDense) {
#pragma unroll
        for (int j = 0; j < 16; ++j) {
            const float wv = zrL[j] - tauL;
            const bool take = wv > 0.f;
            const unsigned long long m = __ballot(take);
            if (take) {
                const int pos = cnt + __popcll(m & ltmask);
                lst[wid][pos] = make_uint2((unsigned)((lane << 4) + j),
                                           __float_as_uint(coefL * wv));
            }
            cnt += __popcll(m);
        }
    }
    // static entries appended (lane-parallel)
    const int nm = (mcW < 64) ? mcW : 64;
    for (int i = lane; i < nm; i += 64) {
        const int ee = mlist[wid][i];
        lst[wid][cnt + i] = make_uint2((unsigned)(ee >> 3),
                                       __float_as_uint(coefS * ewLds[wid][ee & 7]));
    }
    cnt += nm;

    // ----- combined sparse gather, shfl-free, unroll x4 -----
    float ox = 0.f, oy = 0.f, oz2 = 0.f, ow = 0.f;
    int i = 0;
    for (; i + 4 <= cnt; i += 4) {
        const uint2 e0 = lst[wid][i + 0];
        const uint2 e1 = lst[wid][i + 1];
        const uint2 e2 = lst[wid][i + 2];
        const uint2 e3 = lst[wid][i + 3];
        const float4 m0 = *(const float4*)(msgB + (size_t)e0.x * D_ + d4);
        const float4 m1 = *(const float4*)(msgB + (size_t)e1.x * D_ + d4);
        const float4 m2b = *(const float4*)(msgB + (size_t)e2.x * D_ + d4);
        const float4 m3 = *(const float4*)(msgB + (size_t)e3.x * D_ + d4);
        const float w0 = __uint_as_float(e0.y), w1 = __uint_as_float(e1.y);
        const float w2 = __uint_as_float(e2.y), w3 = __uint_as_float(e3.y);
        ox = fmaf(w0, m0.x, fmaf(w1, m1.x, fmaf(w2, m2b.x, fmaf(w3, m3.x, ox))));
        oy = fmaf(w0, m0.y, fmaf(w1, m1.y, fmaf(w2, m2b.y, fmaf(w3, m3.y, oy))));
        oz2 = fmaf(w0, m0.z, fmaf(w1, m1.z, fmaf(w2, m2b.z, fmaf(w3, m3.z, oz2))));
        ow = fmaf(w0, m0.w, fmaf(w1, m1.w, fmaf(w2, m2b.w, fmaf(w3, m3.w, ow))));
    }
    for (; i < cnt; ++i) {
        const uint2 e0 = lst[wid][i];
        const float w0 = __uint_as_float(e0.y);
        const float4 m0 = *(const float4*)(msgB + (size_t)e0.x * D_ + d4);
        ox = fmaf(w0, m0.x, ox); oy = fmaf(w0, m0.y, oy);
        oz2 = fmaf(w0, m0.z, oz2); ow = fmaf(w0, m0.w, ow);
    }

    // ----- dense branches: enqueue for cleanup (or rare overflow fallback) -----
    int slot = -1;
    if (gDense || lDense) {
        int s0 = 0;
        if (lane == 0) s0 = atomicAdd(&qMeta[0], 1);
        slot = __shfl(s0, 0, 64);
    }
    if (slot >= 0 && slot < MAXQ_) {
        // write combined dense weights; raw partial to out; skip epilogue
#pragma unroll
        for (int qd = 0; qd < 4; ++qd) {
            float4 w4;
            float* wv4 = &w4.x;
#pragma unroll
            for (int u = 0; u < 4; ++u) {
                const int j = qd * 4 + u;
                float w = 0.f;
                if (gDense) w += coefG * fmaxf(zrG[j] - tauG, 0.f);
                if (lDense) w += coefL * fmaxf(zrL[j] - tauL, 0.f);
                wv4[u] = w;
            }
            *(float4*)(wq + (size_t)slot * SEQ_ + (lane << 4) + qd * 4) = w4;
        }
        if (lane == 0) qRows[slot] = row;
        *(float4*)(out + (size_t)row * D_ + d4) = make_float4(ox, oy, oz2, ow);
        return;   // wave done (other waves unaffected; no block barriers used)
    }
    if (slot >= MAXQ_) {
        // overflow fallback (effectively never): shfl-walk dense accumulate
#pragma unroll
        for (int j = 0; j < 16; ++j) {
            float wv = 0.f;
            if (gDense) wv += coefG * fmaxf(zrG[j] - tauG, 0.f);
            if (lDense) wv += coefL * fmaxf(zrL[j] - tauL, 0.f);
            unsigned long long m = __ballot(wv > 0.f);
            while (m) {
                const int s0 = __ffsll(m) - 1; m &= m - 1;
                const float w0 = __shfl(wv, s0, 64);
                const float4 m4 = *(const float4*)(msgB + (size_t)((s0 << 4) + j) * D_ + d4);
                ox = fmaf(w0, m4.x, ox); oy = fmaf(w0, m4.y, oy);
                oz2 = fmaf(w0, m4.z, oz2); ow = fmaf(w0, m4.w, ow);
            }
        }
    }

    // ----- epilogue: normalize, probe, rel -----
    float ssq = ox * ox + oy * oy + oz2 * oz2 + ow * ow;
    ssq = waveSum(ssq);
    const float nrm = fmaxf(sqrtf(ssq), 1e-12f);
    const float4 pr = *(const float4*)(wsProbe + (size_t)row * D_ + d4);
    float dp = (ox * pr.x + oy * pr.y + oz2 * pr.z + ow * pr.w) / nrm;
    dp = waveSum(dp);
    const float rel = 1.f / (1.f + expf(-dp));
    *(float4*)(out + (size_t)row * D_ + d4) =
        make_float4(ox * rel, oy * rel, oz2 * rel, ow * rel);
}

// Kernel C: drain dense-row queue. One block per row: branch-free coalesced
// 1024-step GEMV + partial add + epilogue.
__global__ __launch_bounds__(256) void cleanup_kernel(
    const float* __restrict__ messages,
    const float* __restrict__ wsProbe,
    const float* __restrict__ wq,
    const int* __restrict__ qRows,
    int* __restrict__ qMeta,
    float* __restrict__ out)
{
    __shared__ float wsh[SEQ_];
    __shared__ float scr[4];
    __shared__ int idxSh;
    const int tid = threadIdx.x;
    const int nq = (qMeta[0] < MAXQ_) ? qMeta[0] : MAXQ_;
    for (;;) {
        __syncthreads();
        if (tid == 0) idxSh = atomicAdd(&qMeta[1], 1);
        __syncthreads();
        const int idx = idxSh;
        if (idx >= nq) break;
        const int row = qRows[idx];
        const int b = row >> 10;
        const float* msgB = messages + (size_t)b * SEQ_ * D_;
        for (int i = tid; i < SEQ_; i += 256)
            wsh[i] = wq[(size_t)idx * SEQ_ + i];
        __syncthreads();
        float acc = out[(size_t)row * D_ + tid];   // sparse partial from route4
        for (int t = 0; t < SEQ_; t += 4) {
            acc = fmaf(wsh[t + 0], msgB[(size_t)(t + 0) * D_ + tid],
                  fmaf(wsh[t + 1], msgB[(size_t)(t + 1) * D_ + tid],
                  fmaf(wsh[t + 2], msgB[(size_t)(t + 2) * D_ + tid],
                  fmaf(wsh[t + 3], msgB[(size_t)(t + 3) * D_ + tid], acc))));
        }
        const float ssq = blockSum(acc * acc, scr);
        const float nrm = fmaxf(sqrtf(ssq), 1e-12f);
        const float dp = blockSum((acc / nrm) * wsProbe[(size_t)row * D_ + tid], scr);
        const float rel = 1.f / (1.f + expf(-dp));
        out[(size_t)row * D_ + tid] = acc * rel;
    }
}

extern "C" void kernel_launch(void* const* d_in, const int* in_sizes, int n_in,
                              void* d_out, int out_size, void* d_ws, size_t ws_size,
                              hipStream_t stream) {
    const float* messages  = (const float*)d_in[0];
    const float* hidden    = (const float*)d_in[1];
    const int*   x_ids     = (const int*)d_in[2];
    const float* scn       = (const float*)d_in[3];
    const void*  mask      = d_in[4];
    const int*   static_nb = (const int*)d_in[5];
    const float* gvel      = (const float*)d_in[6];
    const float* ctx       = (const float*)d_in[7];
    const float* ent       = (const float*)d_in[8];
    const float* W_vel     = (const float*)d_in[9];
    const float* W_e1      = (const float*)d_in[10];
    const float* b_e1      = (const float*)d_in[11];
    const float* W_e2      = (const float*)d_in[12];
    const float* b_e2      = (const float*)d_in[13];
    const float* W_probe   = (const float*)d_in[14];
    const float* W_gate    = (const float*)d_in[15];
    const float* b_gate    = (const float*)d_in[16];
    float* out = (float*)d_out;
    (void)in_sizes; (void)n_in; (void)out_size; (void)ws_size;

    char* ws = (char*)d_ws;
    size_t o = 0;
    int* flag      = (int*)(ws + o);   o += 256;
    float* wsEnd   = (float*)(ws + o); o += (size_t)B_ * SEQ_ * NS_ * 4;
    float* wsHa    = (float*)(ws + o); o += (size_t)B_ * SEQ_ * D_ * 4;
    float* wsProbe = (float*)(ws + o); o += (size_t)B_ * SEQ_ * D_ * 4;
    int* wsMode    = (int*)(ws + o);   o += (size_t)B_ * SEQ_ * 4;
    float* wsHn    = (float*)(ws + o); o += (size_t)B_ * SEQ_ * 4;
    float* wsGw    = (float*)(ws + o); o += (size_t)B_ * SEQ_ * 4;
    float* msgT    = (float*)(ws + o); o += (size_t)B_ * D_ * SEQ_ * 4;   // 4 MB
    float* scnT    = (float*)(ws + o); o += (size_t)B_ * NS_ * SEQ_ * 4;
    float* WpT     = (float*)(ws + o); o += (size_t)D_ * D_ * 4;
    float* WvT     = (float*)(ws + o); o += (size_t)D_ * NS_ * 4;
    float* zgW     = (float*)(ws + o); o += (size_t)B_ * SEQ_ * SEQ_ * 4;
    float* zlW     = (float*)(ws + o); o += (size_t)B_ * SEQ_ * SEQ_ * 4;
    int* qMeta     = (int*)(ws + o);   o += 256;
    int* qRows     = (int*)(ws + o);   o += (size_t)MAXQ_ * 4;
    // dense-weight buffer overlays msgT (msgT is dead after sims_kernel)
    float* wq      = msgT;             // MAXQ * 1024 * 4 = 4 MB = sizeof(msgT)

    transpose_all<<<dim3(1361), dim3(32, 8), 0, stream>>>(
        messages, scn, W_probe, W_vel, msgT, scnT, WpT, WvT,
        (const unsigned int*)mask, flag, qMeta);
    prep8_kernel<<<dim3(B_ * SEQ_ / 8), dim3(256), 0, stream>>>(
        hidden, scn, gvel, ctx, ent, WpT, WvT, W_gate, b_gate,
        wsEnd, wsHa, wsProbe, wsMode, wsHn, wsGw);
    sims_kernel<<<dim3(512), dim3(512), 0, stream>>>(
        msgT, scnT, scn, wsHa, wsEnd, wsMode, wsHn, mask, flag, zgW, zlW);
    route4_kernel<<<dim3(B_ * SEQ_ / 4), dim3(256), 0, stream>>>(
        messages, scn, x_ids, static_nb, W_e1, b_e1, W_e2, b_e2,
        wsProbe, wsGw, zgW, zlW, wq, qRows, qMeta, out);
    cleanup_kernel<<<dim3(64), dim3(256), 0, stream>>>(
        messages, wsProbe, wq, qRows, qMeta, out);
}

// Round 8
// 172.957 us; speedup vs baseline: 2.0870x; 1.0132x over previous
//
#include <hip/hip_runtime.h>
#include <math.h>

#define D_ 256
#define NS_ 64
#define KNB_ 8
#define SEQ_ 1024
#define B_ 4
#define MAXQ_ 1024
#define KA_ 384            // prescaled A row: [e'(64) | s'(64) | h'(256)]
#define NEG_ (-10000.0f)
#define BLKNEG_ (-50000.0f)

__device__ __forceinline__ float waveSum(float v) {
#pragma unroll
    for (int off = 32; off; off >>= 1) v += __shfl_xor(v, off, 64);
    return v;
}

__device__ __forceinline__ void waveSum2(float& a, float& b) {
#pragma unroll
    for (int off = 32; off; off >>= 1) {
        a += __shfl_xor(a, off, 64);
        b += __shfl_xor(b, off, 64);
    }
}

__device__ __forceinline__ float blockSum(float v, float* scr) {
    const int tid = threadIdx.x;
    const int wid = tid >> 6, lane = tid & 63;
    v = waveSum(v);
    __syncthreads();
    if (lane == 0) scr[wid] = v;
    __syncthreads();
    return scr[0] + scr[1] + scr[2] + scr[3];
}

// batched block-wide sum of 4 independent values (2 barriers total)
__device__ __forceinline__ void blockSum4(float v[4], float (*scr4)[4]) {
    const int tid = threadIdx.x;
    const int wid = tid >> 6, lane = tid & 63;
#pragma unroll
    for (int off = 32; off; off >>= 1) {
#pragma unroll
        for (int q = 0; q < 4; ++q) v[q] += __shfl_xor(v[q], off, 64);
    }
    __syncthreads();
    if (lane == 0) {
#pragma unroll
        for (int q = 0; q < 4; ++q) scr4[wid][q] = v[q];
    }
    __syncthreads();
#pragma unroll
    for (int q = 0; q < 4; ++q)
        v[q] = scr4[0][q] + scr4[1][q] + scr4[2][q] + scr4[3][q];
}

// exact sparsemax tau via support iteration (monotone, fixpoint = exact tau)
__device__ __forceinline__ float sparsemaxTauWave(const float* zr) {
    float mx = zr[0];
#pragma unroll
    for (int i = 1; i < 16; ++i) mx = fmaxf(mx, zr[i]);
#pragma unroll
    for (int off = 32; off; off >>= 1) mx = fmaxf(mx, __shfl_xor(mx, off, 64));
    float tau = mx - 1.0f;
    for (int it = 0; it < 32; ++it) {
        float ssum = 0.f, cnt = 0.f;
#pragma unroll
        for (int i = 0; i < 16; ++i) {
            if (zr[i] > tau) { ssum += zr[i]; cnt += 1.f; }
        }
        waveSum2(ssum, cnt);
        if (cnt < 0.5f) break;                 // safety
        const float nt = (ssum - 1.0f) / cnt;
        if (nt == tau) break;                  // support stable -> exact
        tau = nt;
    }
    return tau;
}

// 4 transposes + mask-dtype detection + queue-counter zeroing in one launch.
__global__ __launch_bounds__(256) void transpose_all(
    const float* __restrict__ messages, const float* __restrict__ scn,
    const float* __restrict__ W_probe, const float* __restrict__ W_vel,
    float* __restrict__ msgT, float* __restrict__ scnT,
    float* __restrict__ WpT, float* __restrict__ WvT,
    const unsigned int* __restrict__ maskW, int* __restrict__ flag,
    int* __restrict__ qMeta)
{
    __shared__ float tile[32][33];
    __shared__ int notI, notF;
    const int bid = blockIdx.x;
    const int tx = threadIdx.x, ty = threadIdx.y;

    if (bid == 1360) {
        const int tid = ty * 32 + tx;
        if (tid == 0) { notI = 0; notF = 0; qMeta[0] = 0; qMeta[1] = 0; }
        __syncthreads();
        int ni = 0, nf = 0;
        for (int i = tid; i < 1024; i += 256) {
            const unsigned int w = maskW[i];
            if (w != 0u && w != 1u) ni = 1;
            if (w != 0u && w != 0x3f800000u) nf = 1;
        }
        if (ni) atomicOr(&notI, 1);
        if (nf) atomicOr(&notF, 1);
        __syncthreads();
        if (tid == 0) *flag = (!notI) ? 0 : ((!notF) ? 2 : 1);
        return;
    }

    const float* src; float* dst; int Rr, Cc, bz, cx, cy;
    if (bid < 1024) {
        const int i = bid; bz = i >> 8; const int rem = i & 255;
        cy = rem >> 3; cx = rem & 7;
        src = messages; dst = msgT; Rr = SEQ_; Cc = D_;
    } else if (bid < 1280) {
        const int i = bid - 1024; bz = i >> 6; const int rem = i & 63;
        cy = rem >> 1; cx = rem & 1;
        src = scn; dst = scnT; Rr = SEQ_; Cc = NS_;
    } else if (bid < 1344) {
        const int i = bid - 1280; bz = 0; cy = i >> 3; cx = i & 7;
        src = W_probe; dst = WpT; Rr = D_; Cc = D_;
    } else {
        const int i = bid - 1344; bz = 0; cy = i >> 1; cx = i & 1;
        src = W_vel; dst = WvT; Rr = D_; Cc = NS_;
    }
    const int c0 = cx << 5, r0 = cy << 5;
    const float* s = src + (size_t)bz * Rr * Cc;
    float* d = dst + (size_t)bz * Rr * Cc;
#pragma unroll
    for (int i = 0; i < 32; i += 8)
        tile[ty + i][tx] = s[(size_t)(r0 + ty + i) * Cc + c0 + tx];
    __syncthreads();
#pragma unroll
    for (int i = 0; i < 32; i += 8)
        d[(size_t)(c0 + ty + i) * Rr + r0 + tx] = tile[tx][ty + i];
}

// merged per-row prep, 8 rows per block (512 blocks).
// Writes prescaled A rows: wsA[row] = [5*Hn*end^ (64) | 5*scn (64) | 2.5*ha^ (256)]
__global__ __launch_bounds__(256) void prep8_kernel(
    const float* __restrict__ hidden,
    const float* __restrict__ scn,
    const float* __restrict__ gvel,
    const float* __restrict__ ctx,
    const float* __restrict__ ent,
    const float* __restrict__ WpT,     // [D][D]
    const float* __restrict__ WvT,     // [NS][D]
    const float* __restrict__ W_gate,
    const float* __restrict__ b_gate,
    float* __restrict__ wsA,           // [4096][KA_]
    float* __restrict__ wsProbe,
    int* __restrict__ wsMode,
    float* __restrict__ wsGw)
{
    __shared__ float scr4[4][4];
    const int rowBase = blockIdx.x << 3;
    const int tid = threadIdx.x;
    const int wid = tid >> 6, lane = tid & 63;
    const float* h0 = hidden + (size_t)rowBase * D_;

    float pr[8] = {};
    for (int e = 0; e < D_; e += 4) {
        const float w0 = WpT[(size_t)(e + 0) * D_ + tid];
        const float w1 = WpT[(size_t)(e + 1) * D_ + tid];
        const float w2 = WpT[(size_t)(e + 2) * D_ + tid];
        const float w3 = WpT[(size_t)(e + 3) * D_ + tid];
#pragma unroll
        for (int r = 0; r < 8; ++r) {
            const float4 h4 = *(const float4*)(h0 + (size_t)r * D_ + e);  // uniform
            pr[r] = fmaf(h4.x, w0, fmaf(h4.y, w1, fmaf(h4.z, w2, fmaf(h4.w, w3, pr[r]))));
        }
    }
    float vh[8] = {};
    for (int e = 0; e < NS_; e += 4) {
        const float w0 = WvT[(size_t)(e + 0) * D_ + tid];
        const float w1 = WvT[(size_t)(e + 1) * D_ + tid];
        const float w2 = WvT[(size_t)(e + 2) * D_ + tid];
        const float w3 = WvT[(size_t)(e + 3) * D_ + tid];
#pragma unroll
        for (int r = 0; r < 8; ++r) {
            const float4 g4 = *(const float4*)(gvel + (size_t)(rowBase + r) * NS_ + e);
            vh[r] = fmaf(g4.x, w0, fmaf(g4.y, w1, fmaf(g4.z, w2, fmaf(g4.w, w3, vh[r]))));
        }
    }

    // per-wave: wave w handles rows 2w, 2w+1 (endpoint, s', argmax, gate)
#pragma unroll
    for (int rr = 0; rr < 2; ++rr) {
        const int r = (wid << 1) + rr, row = rowBase + r;
        const float sv = scn[(size_t)row * NS_ + lane];
        const float gv = gvel[(size_t)row * NS_ + lane];
        const float Hn = ent[row] / 10.373491191781864f;   // log(32000)+1e-8
        const float e = sv + 0.4f * gv;
        const float ss = waveSum(e * e);
        wsA[(size_t)row * KA_ + lane] = (e / fmaxf(sqrtf(ss), 1e-12f)) * 5.0f * Hn;
        wsA[(size_t)row * KA_ + 64 + lane] = 5.0f * sv;
        float v = sv; int idx = lane;
#pragma unroll
        for (int off = 1; off < 64; off <<= 1) {
            const float ov = __shfl_xor(v, off, 64);
            const int   oi = __shfl_xor(idx, off, 64);
            if (ov > v || (ov == v && oi < idx)) { v = ov; idx = oi; }
        }
        float gd = 0.f;
#pragma unroll
        for (int j = 0; j < 4; ++j) {
            const int d = lane + (j << 6);
            gd = fmaf(h0[(size_t)r * D_ + d], W_gate[d], gd);
        }
        gd = waveSum(gd);
        if (lane == 0) {
            wsMode[row] = idx;
            const float raw = 1.f / (1.f + expf(-(gd + b_gate[0])));
            wsGw[row] = raw * ctx[row];
        }
    }

    // block-wide norms, 4 rows per batched reduction
#pragma unroll
    for (int g = 0; g < 2; ++g) {
        float ha4[4], va[4], vp[4];
#pragma unroll
        for (int q = 0; q < 4; ++q) {
            const int r = (g << 2) + q;
            ha4[q] = h0[(size_t)r * D_ + tid] + 0.3f * vh[r];
            va[q] = ha4[q] * ha4[q];
            vp[q] = pr[(g << 2) + q] * pr[(g << 2) + q];
        }
        blockSum4(va, scr4);
        blockSum4(vp, scr4);
#pragma unroll
        for (int q = 0; q < 4; ++q) {
            const int r = (g << 2) + q;
            wsA[(size_t)(rowBase + r) * KA_ + 128 + tid] =
                (ha4[q] / fmaxf(sqrtf(va[q]), 1e-12f)) * 2.5f;
            wsProbe[(size_t)(rowBase + r) * D_ + tid] = pr[r] / fmaxf(sqrtf(vp[q]), 1e-12f);
        }
    }
}

// Kernel A: all-pairs sims -> zg/zl.  16 rows/block, A via wave-uniform
// scalar loads of prescaled wsA (no LDS in the hot loop).
__global__ __launch_bounds__(512) void sims_kernel(
    const float* __restrict__ msgT,     // [B][D][S]
    const float* __restrict__ scnT,     // [B][NS][S]
    const float* __restrict__ wsA,      // [4096][KA_]
    const int* __restrict__ wsMode,
    const void* __restrict__ maskP,
    const int* __restrict__ maskFlag,
    float* __restrict__ zgO,            // [4096][1024]
    float* __restrict__ zlO)            // [4096][1024]
{
    __shared__ int anyMaskSh;
    const int bid = blockIdx.x;          // 256 blocks
    const int b = bid >> 6;
    const int sBase = (bid & 63) << 4;   // 16 rows
    const int rowBase = (b << 10) + sBase;
    const int tid = threadIdx.x;         // 0..511
    const int tcol = tid << 1;           // 2 cols

    if (tid == 0) anyMaskSh = 0;
    __syncthreads();

    const float* msgTb = msgT + (size_t)b * D_ * SEQ_;
    const float* scnTb = scnT + (size_t)b * NS_ * SEQ_;
    const float* A = wsA + (size_t)rowBase * KA_;

    float zg[16][2] = {};
    float zl[16][2] = {};

    // ---- K-loop 1: e' (zg) and s' (zl) against scnT (K=64) ----
    for (int dc = 0; dc < NS_; dc += 4) {
        float2 sv[4];
#pragma unroll
        for (int dj = 0; dj < 4; ++dj)
            sv[dj] = *(const float2*)(scnTb + (size_t)(dc + dj) * SEQ_ + tcol);
#pragma unroll
        for (int r = 0; r < 16; ++r) {
            const float4 e4 = *(const float4*)(A + r * KA_ + dc);        // uniform -> s_load
            const float4 s4 = *(const float4*)(A + r * KA_ + 64 + dc);   // uniform -> s_load
            zg[r][0] = fmaf(e4.x, sv[0].x, fmaf(e4.y, sv[1].x,
                       fmaf(e4.z, sv[2].x, fmaf(e4.w, sv[3].x, zg[r][0]))));
            zg[r][1] = fmaf(e4.x, sv[0].y, fmaf(e4.y, sv[1].y,
                       fmaf(e4.z, sv[2].y, fmaf(e4.w, sv[3].y, zg[r][1]))));
            zl[r][0] = fmaf(s4.x, sv[0].x, fmaf(s4.y, sv[1].x,
                       fmaf(s4.z, sv[2].x, fmaf(s4.w, sv[3].x, zl[r][0]))));
            zl[r][1] = fmaf(s4.x, sv[0].y, fmaf(s4.y, sv[1].y,
                       fmaf(s4.z, sv[2].y, fmaf(s4.w, sv[3].y, zl[r][1]))));
        }
    }
    // ---- K-loop 2: h' (zg) against msgT (K=256) ----
    for (int dc = 0; dc < D_; dc += 4) {
        float2 mv[4];
#pragma unroll
        for (int dj = 0; dj < 4; ++dj)
            mv[dj] = *(const float2*)(msgTb + (size_t)(dc + dj) * SEQ_ + tcol);
#pragma unroll
        for (int r = 0; r < 16; ++r) {
            const float4 h4 = *(const float4*)(A + r * KA_ + 128 + dc);  // uniform -> s_load
            zg[r][0] = fmaf(h4.x, mv[0].x, fmaf(h4.y, mv[1].x,
                       fmaf(h4.z, mv[2].x, fmaf(h4.w, mv[3].x, zg[r][0]))));
            zg[r][1] = fmaf(h4.x, mv[0].y, fmaf(h4.y, mv[1].y,
                       fmaf(h4.z, mv[2].y, fmaf(h4.w, mv[3].y, zg[r][1]))));
        }
    }

    // ---- tail: mask + mode, packed blk bits; write zg; detect hasNb ----
    const int mf = *maskFlag;
    const int2 md2 = *(const int2*)(wsMode + (b << 10) + tcol);
    unsigned blkbits = 0;     // bit (2r+c): col c of row r blocked
    unsigned anybits = 0;     // bit r: this thread saw a same-mode neighbor in row r
#pragma unroll
    for (int r = 0; r < 16; ++r) {
        const int s_r = sBase + r;
        const int row = rowBase + r;
        const int mS = wsMode[row];                   // uniform
        int blk0, blk1;
        const size_t mb = (size_t)s_r * SEQ_ + tcol;
        if (mf == 1) {
            const unsigned char* m8 = (const unsigned char*)maskP;
            blk0 = m8[mb] != 0; blk1 = m8[mb + 1] != 0;
        } else if (mf == 2) {
            const float* mfl = (const float*)maskP;
            blk0 = mfl[mb] != 0.f; blk1 = mfl[mb + 1] != 0.f;
        } else {
            const int* m32 = (const int*)maskP;
            blk0 = m32[mb] != 0; blk1 = m32[mb + 1] != 0;
        }
        if (s_r == tcol) blk0 = 1;
        if (s_r == tcol + 1) blk1 = 1;
        blkbits |= (unsigned)blk0 << (2 * r);
        blkbits |= (unsigned)blk1 << (2 * r + 1);
        const float zg0 = blk0 ? NEG_ : zg[r][0];
        const float zg1 = blk1 ? NEG_ : zg[r][1];
        *(float2*)(zgO + (size_t)row * SEQ_ + tcol) = make_float2(zg0, zg1);
        const int sm0 = (!blk0) && (md2.x == mS);
        const int sm1 = (!blk1) && (md2.y == mS);
        anybits |= (unsigned)(sm0 | sm1) << r;
    }
    if (anybits) atomicOr(&anyMaskSh, (int)anybits);
    __syncthreads();
    const unsigned hasNbMask = (unsigned)anyMaskSh;

#pragma unroll
    for (int r = 0; r < 16; ++r) {
        const int s_r = sBase + r;
        const int row = rowBase + r;
        const int mS = wsMode[row];                   // uniform
        const int blk0 = (blkbits >> (2 * r)) & 1;
        const int blk1 = (blkbits >> (2 * r + 1)) & 1;
        float zl0, zl1;
        if ((hasNbMask >> r) & 1u) {
            const int sm0 = (!blk0) && (md2.x == mS);
            const int sm1 = (!blk1) && (md2.y == mS);
            zl0 = blk0 ? BLKNEG_ : (sm0 ? zl[r][0] : 0.0f);
            zl1 = blk1 ? BLKNEG_ : (sm1 ? zl[r][1] : 0.0f);
        } else {
            zl0 = blk0 ? BLKNEG_ : -0.05f * fabsf((float)(s_r - tcol));
            zl1 = blk1 ? BLKNEG_ : -0.05f * fabsf((float)(s_r - tcol - 1));
        }
        *(float2*)(zlO + (size_t)row * SEQ_ + tcol) = make_float2(zl0, zl1);
    }
}

// Kernel B: 4 waves per block, wave owns one row (mirror-balanced).
// Sparse combined gather; dense-support rows deferred to cleanup via queue.
__global__ __launch_bounds__(256) void route4_kernel(
    const float* __restrict__ messages,
    const float* __restrict__ scn,
    const int* __restrict__ x_ids,
    const int* __restrict__ static_nb,
    const float* __restrict__ W_e1,
    const float* __restrict__ b_e1,
    const float* __restrict__ W_e2,
    const float* __restrict__ b_e2,
    const float* __restrict__ wsProbe,
    const float* __restrict__ wsGw,
    const float* __restrict__ zgA,
    const float* __restrict__ zlA,
    float* __restrict__ wq,          // [MAXQ][1024] dense weights
    int* __restrict__ qRows,
    int* __restrict__ qMeta,         // [0]=tail, [1]=consume
    float* __restrict__ out)
{
    __shared__ uint2 lst[4][256];        // combined (t, weight) entries per wave
    __shared__ float ewLds[4][8];
    __shared__ int   mlist[4][64];

    const int jb = blockIdx.x;               // 0..1023
    const int tid = threadIdx.x;
    const int wid = tid >> 6, lane = tid & 63;
    const int base = jb << 1;
    const int row = (wid == 0) ? base
                  : (wid == 1) ? base + 1
                  : (wid == 2) ? 4094 - base
                               : 4095 - base;
    const int b = row >> 10, s_r = row & 1023;
    const float* msgB = messages + (size_t)b * SEQ_ * D_;
    const float* scnB = scn + (size_t)b * SEQ_ * NS_;
    const unsigned long long ltmask = (1ull << lane) - 1ull;
    const int d4 = lane << 2;

    // ----- issue z loads up-front (latency hidden by static branch) -----
    float zrG[16], zrL[16];
    {
        const float4* zgp = (const float4*)(zgA + (size_t)row * SEQ_ + (lane << 4));
        const float4* zlp = (const float4*)(zlA + (size_t)row * SEQ_ + (lane << 4));
#pragma unroll
        for (int q = 0; q < 4; ++q) {
            const float4 g4 = zgp[q];
            zrG[q * 4 + 0] = g4.x; zrG[q * 4 + 1] = g4.y;
            zrG[q * 4 + 2] = g4.z; zrG[q * 4 + 3] = g4.w;
            const float4 l4 = zlp[q];
            zrL[q * 4 + 0] = l4.x; zrL[q * 4 + 1] = l4.y;
            zrL[q * 4 + 2] = l4.z; zrL[q * 4 + 3] = l4.w;
        }
    }

    // ----- static neighbor-vocab scan: ONE ballot per 64-block (kmask) -----
    const int q = x_ids[row];
    int nb[KNB_];
#pragma unroll
    for (int k = 0; k < KNB_; ++k) nb[k] = static_nb[(size_t)q * KNB_ + k];
    const float ss_l = scnB[(size_t)s_r * NS_ + lane];
    float simk[KNB_] = {};
    unsigned matchedMask = 0;
    int mcW = 0;
    const int* xb = x_ids + (b << 10);
    for (int pb = 0; pb <= s_r; pb += 64) {
        const int p = pb + lane;
        const int id = (p <= s_r) ? xb[p] : -2147483647;
        unsigned kmask = 0;
#pragma unroll
        for (int k = 0; k < KNB_; ++k) kmask |= (id == nb[k]) ? (1u << k) : 0u;
        unsigned long long mb = __ballot(kmask != 0u);
        while (mb) {
            const int src = __ffsll(mb) - 1; mb &= mb - 1;
            const unsigned kms = (unsigned)__shfl((int)kmask, src, 64);
            const int pp = pb + src;
            float pv = scnB[(size_t)pp * NS_ + lane] * ss_l;
            pv = waveSum(pv);
            matchedMask |= kms;
#pragma unroll
            for (int k = 0; k < KNB_; ++k) {
                if ((kms >> k) & 1u) {
                    simk[k] += pv;
                    if (mcW < 64) { if (lane == 0) mlist[wid][mcW] = (pp << 3) | k; ++mcW; }
                }
            }
        }
    }
    // edge MLP: lane = k*8 + j computes one gelu term
    const int kk = lane >> 3, jjn = lane & 7;
    float sv = simk[0];
#pragma unroll
    for (int k = 1; k < KNB_; ++k) sv = (kk == k) ? simk[k] : sv;
    const float xx = sv * W_e1[jjn] + b_e1[jjn];
    float eo = 0.5f * xx * (1.f + erff(xx * 0.70710678118654752f)) * W_e2[jjn];
    eo += __shfl_xor(eo, 1, 64); eo += __shfl_xor(eo, 2, 64); eo += __shfl_xor(eo, 4, 64);
    eo += b_e2[0];
    float m2 = eo;
    m2 = fmaxf(m2, __shfl_xor(m2, 8, 64));
    m2 = fmaxf(m2, __shfl_xor(m2, 16, 64));
    m2 = fmaxf(m2, __shfl_xor(m2, 32, 64));
    const float exv = expf(eo - m2);
    float smv = exv;
    smv += __shfl_xor(smv, 8, 64); smv += __shfl_xor(smv, 16, 64); smv += __shfl_xor(smv, 32, 64);
    if ((lane & 7) == 0) ewLds[wid][kk] = exv / smv;

    const float cov = (float)__popc(matchedMask) * 0.125f;
    const float gw = wsGw[row];
    const float coefG = gw;
    const float coefL = (1.f - gw) * (1.f - cov);
    const float coefS = (1.f - gw) * cov;

    // ----- sparsemax taus + support sizes -----
    const float tauG = sparsemaxTauWave(zrG);
    int supG = 0;
#pragma unroll
    for (int j = 0; j < 16; ++j) supG += __popcll(__ballot(zrG[j] > tauG));
    const float tauL = sparsemaxTauWave(zrL);
    int supL = 0;
#pragma unroll
    for (int j = 0; j < 16; ++j) supL += __popcll(__ballot(zrL[j] > tauL));
    const bool gDense = supG > 96;
    const bool lDense = supL > 96;

    // ----- sparse list build (only for non-dense branches) -----
    int cnt = 0;
    if (!gDense) {
#pragma unroll
        for (int j = 0; j < 16; ++j) {
            const float wv = zrG[j] - tauG;
            const bool take = wv > 0.f;
            const unsigned long long m = __ballot(take);
            if (take) {
                const int pos = cnt + __popcll(m & ltmask);
                lst[wid][pos] = make_uint2((unsigned)((lane << 4) + j),
                                           __float_as_uint(coefG * wv));
            }
            cnt += __popcll(m);
        }
    }
    if (!lDense) {
#pragma unroll
        for (int j = 0; j < 16; ++j) {
            const float wv = zrL[j] - tauL;
            const bool take = wv > 0.f;
            const unsigned long long m = __ballot(take);
            if (take) {
                const int pos = cnt + __popcll(m & ltmask);
                lst[wid][pos] = make_uint2((unsigned)((lane << 4) + j),
                                           __float_as_uint(coefL * wv));
            }
            cnt += __popcll(m);
        }
    }
    // static entries appended (lane-parallel)
    const int nm = (mcW < 64) ? mcW : 64;
    for (int i = lane; i < nm; i += 64) {
        const int ee = mlist[wid][i];
        lst[wid][cnt + i] = make_uint2((unsigned)(ee >> 3),
                                       __float_as_uint(coefS * ewLds[wid][ee & 7]));
    }
    cnt += nm;

    // ----- combined sparse gather, shfl-free, unroll x4 -----
    float ox = 0.f, oy = 0.f, oz2 = 0.f, ow = 0.f;
    int i = 0;
    for (; i + 4 <= cnt; i += 4) {
        const uint2 e0 = lst[wid][i + 0];
        const uint2 e1 = lst[wid][i + 1];
        const uint2 e2 = lst[wid][i + 2];
        const uint2 e3 = lst[wid][i + 3];
        const float4 m0 = *(const float4*)(msgB + (size_t)e0.x * D_ + d4);
        const float4 m1 = *(const float4*)(msgB + (size_t)e1.x * D_ + d4);
        const float4 m2b = *(const float4*)(msgB + (size_t)e2.x * D_ + d4);
        const float4 m3 = *(const float4*)(msgB + (size_t)e3.x * D_ + d4);
        const float w0 = __uint_as_float(e0.y), w1 = __uint_as_float(e1.y);
        const float w2 = __uint_as_float(e2.y), w3 = __uint_as_float(e3.y);
        ox = fmaf(w0, m0.x, fmaf(w1, m1.x, fmaf(w2, m2b.x, fmaf(w3, m3.x, ox))));
        oy = fmaf(w0, m0.y, fmaf(w1, m1.y, fmaf(w2, m2b.y, fmaf(w3, m3.y, oy))));
        oz2 = fmaf(w0, m0.z, fmaf(w1, m1.z, fmaf(w2, m2b.z, fmaf(w3, m3.z, oz2))));
        ow = fmaf(w0, m0.w, fmaf(w1, m1.w, fmaf(w2, m2b.w, fmaf(w3, m3.w, ow))));
    }
    for (; i < cnt; ++i) {
        const uint2 e0 = lst[wid][i];
        const float w0 = __uint_as_float(e0.y);
        const float4 m0 = *(const float4*)(msgB + (size_t)e0.x * D_ + d4);
        ox = fmaf(w0, m0.x, ox); oy = fmaf(w0, m0.y, oy);
        oz2 = fmaf(w0, m0.z, oz2); ow = fmaf(w0, m0.w, ow);
    }

    // ----- dense branches: enqueue for cleanup (or rare overflow fallback) -----
    int slot = -1;
    if (gDense || lDense) {
        int s0 = 0;
        if (lane == 0) s0 = atomicAdd(&qMeta[0], 1);
        slot = __shfl(s0, 0, 64);
    }
    if (slot >= 0 && slot < MAXQ_) {
        // write combined dense weights; raw partial to out; skip epilogue
#pragma unroll
        for (int qd = 0; qd < 4; ++qd) {
            float4 w4;
            float* wv4 = &w4.x;
#pragma unroll
            for (int u = 0; u < 4; ++u) {
                const int j = qd * 4 + u;
                float w = 0.f;
                if (gDense) w += coefG * fmaxf(zrG[j] - tauG, 0.f);
                if (lDense) w += coefL * fmaxf(zrL[j] - tauL, 0.f);
                wv4[u] = w;
            }
            *(float4*)(wq + (size_t)slot * SEQ_ + (lane << 4) + qd * 4) = w4;
        }
        if (lane == 0) qRows[slot] = row;
        *(float4*)(out + (size_t)row * D_ + d4) = make_float4(ox, oy, oz2, ow);
        return;   // wave done (other waves unaffected; no block barriers used)
    }
    if (slot >= MAXQ_) {
        // overflow fallback (effectively never): shfl-walk dense accumulate
#pragma unroll
        for (int j = 0; j < 16; ++j) {
            float wv = 0.f;
            if (gDense) wv += coefG * fmaxf(zrG[j] - tauG, 0.f);
            if (lDense) wv += coefL * fmaxf(zrL[j] - tauL, 0.f);
            unsigned long long m = __ballot(wv > 0.f);
            while (m) {
                const int s0 = __ffsll(m) - 1; m &= m - 1;
                const float w0 = __shfl(wv, s0, 64);
                const float4 m4 = *(const float4*)(msgB + (size_t)((s0 << 4) + j) * D_ + d4);
                ox = fmaf(w0, m4.x, ox); oy = fmaf(w0, m4.y, oy);
                oz2 = fmaf(w0, m4.z, oz2); ow = fmaf(w0, m4.w, ow);
            }
        }
    }

    // ----- epilogue: normalize, probe, rel -----
    float ssq = ox * ox + oy * oy + oz2 * oz2 + ow * ow;
    ssq = waveSum(ssq);
    const float nrm = fmaxf(sqrtf(ssq), 1e-12f);
    const float4 pr = *(const float4*)(wsProbe + (size_t)row * D_ + d4);
    float dp = (ox * pr.x + oy * pr.y + oz2 * pr.z + ow * pr.w) / nrm;
    dp = waveSum(dp);
    const float rel = 1.f / (1.f + expf(-dp));
    *(float4*)(out + (size_t)row * D_ + d4) =
        make_float4(ox * rel, oy * rel, oz2 * rel, ow * rel);
}

// Kernel C: drain dense-row queue. One block per row: branch-free coalesced
// 1024-step GEMV + partial add + epilogue.
__global__ __launch_bounds__(256) void cleanup_kernel(
    const float* __restrict__ messages,
    const float* __restrict__ wsProbe,
    const float* __restrict__ wq,
    const int* __restrict__ qRows,
    int* __restrict__ qMeta,
    float* __restrict__ out)
{
    __shared__ float wsh[SEQ_];
    __shared__ float scr[4];
    __shared__ int idxSh;
    const int tid = threadIdx.x;
    const int nq = (qMeta[0] < MAXQ_) ? qMeta[0] : MAXQ_;
    for (;;) {
        __syncthreads();
        if (tid == 0) idxSh = atomicAdd(&qMeta[1], 1);
        __syncthreads();
        const int idx = idxSh;
        if (idx >= nq) break;
        const int row = qRows[idx];
        const int b = row >> 10;
        const float* msgB = messages + (size_t)b * SEQ_ * D_;
        for (int i = tid; i < SEQ_; i += 256)
            wsh[i] = wq[(size_t)idx * SEQ_ + i];
        __syncthreads();
        float acc = out[(size_t)row * D_ + tid];   // sparse partial from route4
        for (int t = 0; t < SEQ_; t += 4) {
            acc = fmaf(wsh[t + 0], msgB[(size_t)(t + 0) * D_ + tid],
                  fmaf(wsh[t + 1], msgB[(size_t)(t + 1) * D_ + tid],
                  fmaf(wsh[t + 2], msgB[(size_t)(t + 2) * D_ + tid],
                  fmaf(wsh[t + 3], msgB[(size_t)(t + 3) * D_ + tid], acc))));
        }
        const float ssq = blockSum(acc * acc, scr);
        const float nrm = fmaxf(sqrtf(ssq), 1e-12f);
        const float dp = blockSum((acc / nrm) * wsProbe[(size_t)row * D_ + tid], scr);
        const float rel = 1.f / (1.f + expf(-dp));
        out[(size_t)row * D_ + tid] = acc * rel;
    }
}

extern "C" void kernel_launch(void* const* d_in, const int* in_sizes, int n_in,
                              void* d_out, int out_size, void* d_ws, size_t ws_size,
                              hipStream_t stream) {
    const float* messages  = (const float*)d_in[0];
    const float* hidden    = (const float*)d_in[1];
    const int*   x_ids     = (const int*)d_in[2];
    const float* scn       = (const float*)d_in[3];
    const void*  mask      = d_in[4];
    const int*   static_nb = (const int*)d_in[5];
    const float* gvel      = (const float*)d_in[6];
    const float* ctx       = (const float*)d_in[7];
    const float* ent       = (const float*)d_in[8];
    const float* W_vel     = (const float*)d_in[9];
    const float* W_e1      = (const float*)d_in[10];
    const float* b_e1      = (const float*)d_in[11];
    const float* W_e2      = (const float*)d_in[12];
    const float* b_e2      = (const float*)d_in[13];
    const float* W_probe   = (const float*)d_in[14];
    const float* W_gate    = (const float*)d_in[15];
    const float* b_gate    = (const float*)d_in[16];
    float* out = (float*)d_out;
    (void)in_sizes; (void)n_in; (void)out_size; (void)ws_size;

    char* ws = (char*)d_ws;
    size_t o = 0;
    int* flag      = (int*)(ws + o);   o += 256;
    float* wsA     = (float*)(ws + o); o += (size_t)B_ * SEQ_ * KA_ * 4;   // 6.3 MB
    float* wsProbe = (float*)(ws + o); o += (size_t)B_ * SEQ_ * D_ * 4;
    int* wsMode    = (int*)(ws + o);   o += (size_t)B_ * SEQ_ * 4;
    float* wsGw    = (float*)(ws + o); o += (size_t)B_ * SEQ_ * 4;
    float* msgT    = (float*)(ws + o); o += (size_t)B_ * D_ * SEQ_ * 4;    // 4 MB
    float* scnT    = (float*)(ws + o); o += (size_t)B_ * NS_ * SEQ_ * 4;
    float* WpT     = (float*)(ws + o); o += (size_t)D_ * D_ * 4;
    float* WvT     = (float*)(ws + o); o += (size_t)D_ * NS_ * 4;
    float* zgW     = (float*)(ws + o); o += (size_t)B_ * SEQ_ * SEQ_ * 4;
    float* zlW     = (float*)(ws + o); o += (size_t)B_ * SEQ_ * SEQ_ * 4;
    int* qMeta     = (int*)(ws + o);   o += 256;
    int* qRows     = (int*)(ws + o);   o += (size_t)MAXQ_ * 4;
    // dense-weight buffer overlays msgT (msgT is dead after sims_kernel)
    float* wq      = msgT;             // MAXQ * 1024 * 4 = 4 MB = sizeof(msgT)

    transpose_all<<<dim3(1361), dim3(32, 8), 0, stream>>>(
        messages, scn, W_probe, W_vel, msgT, scnT, WpT, WvT,
        (const unsigned int*)mask, flag, qMeta);
    prep8_kernel<<<dim3(B_ * SEQ_ / 8), dim3(256), 0, stream>>>(
        hidden, scn, gvel, ctx, ent, WpT, WvT, W_gate, b_gate,
        wsA, wsProbe, wsMode, wsGw);
    sims_kernel<<<dim3(256), dim3(512), 0, stream>>>(
        msgT, scnT, wsA, wsMode, mask, flag, zgW, zlW);
    route4_kernel<<<dim3(B_ * SEQ_ / 4), dim3(256), 0, stream>>>(
        messages, scn, x_ids, static_nb, W_e1, b_e1, W_e2, b_e2,
        wsProbe, wsGw, zgW, zlW, wq, qRows, qMeta, out);
    cleanup_kernel<<<dim3(64), dim3(256), 0, stream>>>(
        messages, wsProbe, wq, qRows, qMeta, out);
}